// Round 13
// baseline (324.254 us; speedup 1.0000x reference)
//
#include <hip/hip_runtime.h>
#include <math.h>

#define NNODES 50000
#define NEDGES 800000
#define DIN 256
#define DHID 128
#define GBLK 391   // gemm_in row blocks = ceil(50000/128)
#define QBLK 782   // gemm_qkvs row blocks = ceil(50000/64)
#define NBUCK 196  // ceil(50000/256) dst buckets
#define CHUNK 4096 // edges per bin_edges block

typedef __attribute__((ext_vector_type(8))) short short8;
typedef __attribute__((ext_vector_type(4))) float f32x4;
typedef __attribute__((ext_vector_type(2))) float f32x2;

__device__ __forceinline__ unsigned short f2bf(float f) {
    unsigned u = __builtin_bit_cast(unsigned, f);
    u += 0x7fffu + ((u >> 16) & 1u);  // RNE
    return (unsigned short)(u >> 16);
}
__device__ __forceinline__ float bf2f(unsigned short s) {
    return __builtin_bit_cast(float, (unsigned)s << 16);
}
__device__ __forceinline__ unsigned packbf(float a, float b) {
    return (unsigned)f2bf(a) | ((unsigned)f2bf(b) << 16);
}
// DPP helpers: full-rate VALU cross-lane (no LDS)
__device__ __forceinline__ float dpp_xor1(float x) {  // quad_perm [1,0,3,2]
    return __builtin_bit_cast(float, __builtin_amdgcn_update_dpp(0, __builtin_bit_cast(int, x), 0xB1, 0xF, 0xF, true));
}
__device__ __forceinline__ float dpp_xor2(float x) {  // quad_perm [2,3,0,1]
    return __builtin_bit_cast(float, __builtin_amdgcn_update_dpp(0, __builtin_bit_cast(int, x), 0x4E, 0xF, 0xF, true));
}
__device__ __forceinline__ float dpp_hmirror(float x) {  // row_half_mirror
    return __builtin_bit_cast(float, __builtin_amdgcn_update_dpp(0, __builtin_bit_cast(int, x), 0x141, 0xF, 0xF, true));
}
__device__ __forceinline__ float dpp_mirror(float x) {  // row_mirror
    return __builtin_bit_cast(float, __builtin_amdgcn_update_dpp(0, __builtin_bit_cast(int, x), 0x140, 0xF, 0xF, true));
}
__device__ __forceinline__ float red16(float x) {
    x += dpp_xor1(x);
    x += dpp_xor2(x);
    x += dpp_hmirror(x);
    x += dpp_mirror(x);
    return x;
}

// ---------------- weight prep (blocks < pb) + degree histogram (blocks >= pb) ----------------
__global__ __launch_bounds__(256) void prep_hist(const float* __restrict__ Wi, const float* __restrict__ Wq,
                                                 const float* __restrict__ Wk, const float* __restrict__ Wv,
                                                 const float* __restrict__ Ws, unsigned short* __restrict__ Wit,
                                                 unsigned short* __restrict__ Wt3, const int* __restrict__ dst,
                                                 int* __restrict__ counts, int pb) {
    if ((int)blockIdx.x < pb) {
        int idx = blockIdx.x * 256 + threadIdx.x;
        if (idx < DHID * DIN) {
            int n = idx >> 8, kk = idx & 255;
            Wit[idx] = f2bf(Wi[kk * DHID + n]);
        }
        int idx2 = idx - DHID * DIN;
        if (idx2 >= 0 && idx2 < 3 * 512 * DHID) {
            int l = idx2 / (512 * DHID);
            int rem = idx2 - l * 512 * DHID;
            int r = rem >> 7;
            int kk = rem & 127;
            int sel = r >> 7, rl = r & 127;
            const float* srcm = sel == 0 ? Wq : sel == 1 ? Wk : sel == 2 ? Wv : Ws;
            Wt3[idx2] = f2bf(srcm[l * DHID * DHID + kk * DHID + rl]);
        }
    } else {
        int e = (blockIdx.x - pb) * 256 + threadIdx.x;
        if (e < NEDGES) atomicAdd(&counts[dst[e]], 1);
    }
}

// scan counts -> row_ptr+1 partials; ALSO accumulate degree histogram (deg clamp 255) into dh
__global__ __launch_bounds__(256) void k_scan_block(const int* __restrict__ in, int* __restrict__ out,
                                                    int* __restrict__ partials, int n, int* __restrict__ dh) {
    __shared__ int sh[256];
    __shared__ int dhist[256];
    int tid = threadIdx.x;
    int i = blockIdx.x * 256 + tid;
    int vv = (i < n) ? in[i] : 0;
    sh[tid] = vv;
    dhist[tid] = 0;
    __syncthreads();
    if (i < n) atomicAdd(&dhist[min(vv, 255)], 1);
    for (int off = 1; off < 256; off <<= 1) {
        int t = (tid >= off) ? sh[tid - off] : 0;
        __syncthreads();
        sh[tid] += t;
        __syncthreads();
    }
    if (i < n) out[i] = sh[tid];
    if (tid == 255) partials[blockIdx.x] = sh[255];
    __syncthreads();
    int hc = dhist[tid];
    if (hc) atomicAdd(&dh[tid], hc);
}

// apply block prefixes to row_ptr; block 0 also builds dbase = descending-degree exclusive prefix of dh
__global__ __launch_bounds__(256) void k_apply2(const int* __restrict__ partials, int* __restrict__ row_ptr, int n,
                                                int nb, const int* __restrict__ dh, int* __restrict__ dbase) {
    __shared__ int sh[256];
    int tid = threadIdx.x;
    int vv = (tid < nb) ? partials[tid] : 0;
    sh[tid] = vv;
    __syncthreads();
    for (int off = 1; off < 256; off <<= 1) {
        int t = (tid >= off) ? sh[tid - off] : 0;
        __syncthreads();
        sh[tid] += t;
        __syncthreads();
    }
    int i = blockIdx.x * 256 + tid;
    if (i < n) {
        int add = blockIdx.x ? sh[blockIdx.x - 1] : 0;
        row_ptr[i + 1] += add;
    }
    if (i == 0) row_ptr[0] = 0;
    if (blockIdx.x == 0) {
        __syncthreads();
        int c = dh[255 - tid];
        sh[tid] = c;
        __syncthreads();
        for (int off = 1; off < 256; off <<= 1) {
            int t = (tid >= off) ? sh[tid - off] : 0;
            __syncthreads();
            sh[tid] += t;
            __syncthreads();
        }
        dbase[255 - tid] = sh[tid] - c;  // exclusive prefix, highest degree first
    }
}

// LPT permutation: perm = node ids sorted by degree descending (LDS-aggregated counting sort)
__global__ __launch_bounds__(256) void perm_scatter(const int* __restrict__ counts, const int* __restrict__ dbase,
                                                    int* __restrict__ dfill, int* __restrict__ perm) {
    __shared__ int h[256], gb[256], c2[256];
    const int tid = threadIdx.x;
    int i = blockIdx.x * 256 + tid;
    int d = (i < NNODES) ? min(counts[i], 255) : -1;
    h[tid] = 0;
    c2[tid] = 0;
    __syncthreads();
    if (d >= 0) atomicAdd(&h[d], 1);
    __syncthreads();
    int c = h[tid];
    gb[tid] = c ? dbase[tid] + atomicAdd(&dfill[tid], c) : 0;
    __syncthreads();
    if (d >= 0) {
        int r = atomicAdd(&c2[d], 1);
        perm[gb[d] + r] = i;
    }
}

// ---------------- pass A: bin edges by dst>>8 into bucket-grouped intermediate (coalesced writes) ----------------
__global__ __launch_bounds__(256) void bin_edges(const int* __restrict__ src, const int* __restrict__ dst,
                                                 const float* __restrict__ ea, const int* __restrict__ row_ptr,
                                                 int* __restrict__ bfill, unsigned* __restrict__ brec,
                                                 unsigned char* __restrict__ bdst) {
    __shared__ int hist[NBUCK];
    __shared__ int lbase[NBUCK];
    __shared__ int gbase[NBUCK];
    __shared__ int cnt[NBUCK];
    __shared__ unsigned rec4[CHUNK];
    __shared__ unsigned char dl8[CHUNK];
    __shared__ unsigned char bk8[CHUNK];
    const int tid = threadIdx.x;
    const int e0 = blockIdx.x * CHUNK;
    const int n = min(NEDGES - e0, CHUNK);
    for (int i = tid; i < NBUCK; i += 256) hist[i] = 0;
    __syncthreads();
    for (int i = tid; i < n; i += 256) atomicAdd(&hist[dst[e0 + i] >> 8], 1);
    __syncthreads();
    if (tid == 0) {
        int run = 0;
        for (int b = 0; b < NBUCK; ++b) {
            lbase[b] = run;
            run += hist[b];
        }
    }
    __syncthreads();
    for (int b = tid; b < NBUCK; b += 256) {
        int h = hist[b];
        int off = h ? atomicAdd(&bfill[b], h) : 0;
        gbase[b] = row_ptr[b << 8] + off;
        cnt[b] = lbase[b];
    }
    __syncthreads();
    for (int i = tid; i < n; i += 256) {
        int d = dst[e0 + i];
        int b = d >> 8;
        int lp = atomicAdd(&cnt[b], 1);
        rec4[lp] = (unsigned)src[e0 + i] | ((unsigned)f2bf(ea[e0 + i]) << 16);
        dl8[lp] = (unsigned char)(d & 255);
        bk8[lp] = (unsigned char)b;
    }
    __syncthreads();
    for (int i = tid; i < n; i += 256) {
        int b = bk8[i];
        int pos = gbase[b] + (i - lbase[b]);
        brec[pos] = rec4[i];
        bdst[pos] = dl8[i];
    }
}

// ---------------- pass B: within-bucket counting sort; all stores confined to one block's window ----------------
__global__ __launch_bounds__(256) void sort_bucket(const unsigned* __restrict__ brec,
                                                   const unsigned char* __restrict__ bdst,
                                                   const int* __restrict__ row_ptr, unsigned* __restrict__ esrc) {
    __shared__ int rp[257];
    __shared__ int cnt[256];
    const int b = blockIdx.x;
    const int d0 = b << 8;
    const int nmax = min(256, NNODES - d0);
    const int tid = threadIdx.x;
    for (int i = tid; i <= nmax; i += 256) rp[i] = row_ptr[d0 + i];
    cnt[tid] = 0;
    __syncthreads();
    const int base = rp[0], end = rp[nmax];
    for (int i = base + tid; i < end; i += 256) {
        unsigned rec = brec[i];
        int d = bdst[i];
        int rank = atomicAdd(&cnt[d], 1);
        esrc[rp[d] + rank] = rec;
    }
}

// ---------------- input projection: h[M,128](bf16) = x[M,256] @ Wi + bi ----------------
__global__ __launch_bounds__(256) void gemm_in(const float* __restrict__ A, const unsigned short* __restrict__ Wt,
                                               const float* __restrict__ bias, unsigned* __restrict__ h32, int M) {
    __shared__ short As[128 * 128];
    const int tid = threadIdx.x;
    const int lane = tid & 63;
    const int wid = tid >> 6;
    const int row0 = blockIdx.x * 128;
    const int wr = (wid & 1) * 64;
    const int wc = (wid >> 1) * 64;
    f32x4 acc[4][4] = {};
    const int srow = tid >> 1;
    const int sk = (tid & 1) * 64;
    const int grow = min(row0 + srow, M - 1);
    for (int kt = 0; kt < 2; ++kt) {
        const float* ap = A + (size_t)grow * DIN + kt * 128 + sk;
#pragma unroll
        for (int i = 0; i < 8; ++i) {
            float4 f0 = *(const float4*)(ap + i * 8);
            float4 f1 = *(const float4*)(ap + i * 8 + 4);
            short8 s;
            s[0] = f2bf(f0.x); s[1] = f2bf(f0.y); s[2] = f2bf(f0.z); s[3] = f2bf(f0.w);
            s[4] = f2bf(f1.x); s[5] = f2bf(f1.y); s[6] = f2bf(f1.z); s[7] = f2bf(f1.w);
            int g = (sk >> 3) + i;
            *(short8*)(&As[srow * 128 + ((g ^ (srow & 7)) << 3)]) = s;
        }
        __syncthreads();
#pragma unroll
        for (int ks = 0; ks < 4; ++ks) {
            short8 a[4], b[4];
#pragma unroll
            for (int m = 0; m < 4; ++m) {
                int r = wr + m * 16 + (lane & 15);
                int g = ks * 4 + (lane >> 4);
                a[m] = *(const short8*)(&As[r * 128 + ((g ^ (r & 7)) << 3)]);
            }
#pragma unroll
            for (int n = 0; n < 4; ++n) {
                int c = wc + n * 16 + (lane & 15);
                b[n] = *(const short8*)(Wt + (size_t)c * DIN + kt * 128 + ks * 32 + (lane >> 4) * 8);
            }
#pragma unroll
            for (int m = 0; m < 4; ++m)
#pragma unroll
                for (int n = 0; n < 4; ++n)
                    acc[m][n] = __builtin_amdgcn_mfma_f32_16x16x32_bf16(a[m], b[n], acc[m][n], 0, 0, 0);
        }
        __syncthreads();
    }
    // epilogue: per-wave LDS repack (reuse As) -> coalesced uint4 stores
    float* my = ((float*)As) + wid * 1024;
    float bb[4];
#pragma unroll
    for (int n = 0; n < 4; ++n) bb[n] = bias[wc + n * 16 + (lane & 15)];
    const int rr = lane >> 2;
    const int cb = lane & 3;
#pragma unroll
    for (int m = 0; m < 4; ++m) {
#pragma unroll
        for (int n = 0; n < 4; ++n) {
            int lc = n * 16 + (lane & 15);
#pragma unroll
            for (int j = 0; j < 4; ++j) {
                int row = (lane >> 4) * 4 + j;
                my[row * 64 + (((lc >> 2) ^ (row & 7)) << 2) + (lc & 3)] = acc[m][n][j] + bb[n];
            }
        }
        float vals[16];
#pragma unroll
        for (int s = 0; s < 4; ++s) {
            int gx = (cb * 4 + s) ^ (rr & 7);
            f32x4 t4 = *(const f32x4*)(my + rr * 64 + gx * 4);
            vals[s * 4 + 0] = t4.x; vals[s * 4 + 1] = t4.y; vals[s * 4 + 2] = t4.z; vals[s * 4 + 3] = t4.w;
        }
        int grow2 = row0 + wr + m * 16 + rr;
        if (grow2 < M) {
            unsigned pk[8];
#pragma unroll
            for (int d = 0; d < 8; ++d) pk[d] = packbf(vals[2 * d], vals[2 * d + 1]);
            unsigned* op = h32 + (size_t)grow2 * 64 + (wc >> 1) + cb * 8;
            *(uint4*)op = make_uint4(pk[0], pk[1], pk[2], pk[3]);
            *(uint4*)(op + 4) = make_uint4(pk[4], pk[5], pk[6], pk[7]);
        }
    }
}

// ---------------- fused q/k/v/skip GEMM from bf16 h: 64-row blocks, 4 waves (balanced packing) ----------------
__global__ __launch_bounds__(256) void gemm_qkvs(const unsigned short* __restrict__ A,
                                                 const unsigned short* __restrict__ Wt, const float* __restrict__ bq,
                                                 const float* __restrict__ bk, const float* __restrict__ bv,
                                                 const float* __restrict__ bs, unsigned* __restrict__ q32,
                                                 unsigned* __restrict__ kv, unsigned* __restrict__ xr32, int M) {
    __shared__ short As[64 * 128];  // 16 KB
    const int tid = threadIdx.x;
    const int lane = tid & 63;
    const int wid = tid >> 6;  // 0..3
    const int row0 = blockIdx.x * 64;
    const int sel = wid >> 1;        // 0: q/skip, 1: k/v
    const int wc = (wid & 1) * 64;   // col half within the pair's 128 cols
    f32x4 acc0[4][4] = {}, acc1[4][4] = {};
    {
        const int srow = tid >> 2;        // 0..63
        const int sk = (tid & 3) * 32;
        const int grow = min(row0 + srow, M - 1);
        const unsigned short* ap = A + (size_t)grow * DHID + sk;
#pragma unroll
        for (int i = 0; i < 4; ++i) {
            short8 s = *(const short8*)(ap + i * 8);
            int g = (sk >> 3) + i;
            *(short8*)(&As[srow * 128 + ((g ^ (srow & 7)) << 3)]) = s;
        }
    }
    __syncthreads();
    const int b0base = sel ? 128 : 0;    // k : q
    const int b1base = sel ? 256 : 384;  // v : skip
#pragma unroll
    for (int ks = 0; ks < 4; ++ks) {
        short8 a[4], b0[4], b1[4];
#pragma unroll
        for (int m = 0; m < 4; ++m) {
            int r = m * 16 + (lane & 15);
            int g = ks * 4 + (lane >> 4);
            a[m] = *(const short8*)(&As[r * 128 + ((g ^ (r & 7)) << 3)]);
        }
#pragma unroll
        for (int n = 0; n < 4; ++n) {
            int rb = wc + n * 16 + (lane & 15);
            b0[n] = *(const short8*)(Wt + (size_t)(b0base + rb) * DHID + ks * 32 + (lane >> 4) * 8);
            b1[n] = *(const short8*)(Wt + (size_t)(b1base + rb) * DHID + ks * 32 + (lane >> 4) * 8);
        }
#pragma unroll
        for (int m = 0; m < 4; ++m)
#pragma unroll
            for (int n = 0; n < 4; ++n) {
                acc0[m][n] = __builtin_amdgcn_mfma_f32_16x16x32_bf16(a[m], b0[n], acc0[m][n], 0, 0, 0);
                acc1[m][n] = __builtin_amdgcn_mfma_f32_16x16x32_bf16(a[m], b1[n], acc1[m][n], 0, 0, 0);
            }
    }
    __syncthreads();  // done reading As; reuse as repack buffer (4 waves x 4 KB = 16 KB)
    float* my = ((float*)As) + wid * 1024;
    const float* bias0 = sel ? bk : bq;
    const float* bias1 = sel ? bv : bs;
    float bb0[4], bb1[4];
#pragma unroll
    for (int n = 0; n < 4; ++n) {
        int c = wc + n * 16 + (lane & 15);
        bb0[n] = bias0[c];
        bb1[n] = bias1[c];
    }
    const int rr = lane >> 2;
    const int cb = lane & 3;
#pragma unroll
    for (int m = 0; m < 4; ++m) {
        float vals0[16], vals1[16];
#pragma unroll
        for (int n = 0; n < 4; ++n) {
            int lc = n * 16 + (lane & 15);
#pragma unroll
            for (int j = 0; j < 4; ++j) {
                int row = (lane >> 4) * 4 + j;
                my[row * 64 + (((lc >> 2) ^ (row & 7)) << 2) + (lc & 3)] = acc0[m][n][j] + bb0[n];
            }
        }
#pragma unroll
        for (int s = 0; s < 4; ++s) {
            int gx = (cb * 4 + s) ^ (rr & 7);
            f32x4 t4 = *(const f32x4*)(my + rr * 64 + gx * 4);
            vals0[s * 4 + 0] = t4.x; vals0[s * 4 + 1] = t4.y; vals0[s * 4 + 2] = t4.z; vals0[s * 4 + 3] = t4.w;
        }
#pragma unroll
        for (int n = 0; n < 4; ++n) {
            int lc = n * 16 + (lane & 15);
#pragma unroll
            for (int j = 0; j < 4; ++j) {
                int row = (lane >> 4) * 4 + j;
                my[row * 64 + (((lc >> 2) ^ (row & 7)) << 2) + (lc & 3)] = acc1[m][n][j] + bb1[n];
            }
        }
#pragma unroll
        for (int s = 0; s < 4; ++s) {
            int gx = (cb * 4 + s) ^ (rr & 7);
            f32x4 t4 = *(const f32x4*)(my + rr * 64 + gx * 4);
            vals1[s * 4 + 0] = t4.x; vals1[s * 4 + 1] = t4.y; vals1[s * 4 + 2] = t4.z; vals1[s * 4 + 3] = t4.w;
        }
        int grow2 = row0 + m * 16 + rr;
        if (grow2 < M) {
            size_t obase = (size_t)grow2 * 64 + (wc >> 1) + cb * 8;
            if (sel == 0) {
                unsigned p0[8], p1[8];
#pragma unroll
                for (int d = 0; d < 8; ++d) {
                    p0[d] = packbf(vals0[2 * d], vals0[2 * d + 1]);
                    p1[d] = packbf(vals1[2 * d], vals1[2 * d + 1]);
                }
                *(uint4*)(q32 + obase) = make_uint4(p0[0], p0[1], p0[2], p0[3]);
                *(uint4*)(q32 + obase + 4) = make_uint4(p0[4], p0[5], p0[6], p0[7]);
                *(uint4*)(xr32 + obase) = make_uint4(p1[0], p1[1], p1[2], p1[3]);
                *(uint4*)(xr32 + obase + 4) = make_uint4(p1[4], p1[5], p1[6], p1[7]);
            } else {
                unsigned pk[8];
#pragma unroll
                for (int d = 0; d < 8; ++d) {
                    unsigned u = (unsigned)__builtin_amdgcn_cvt_pk_fp8_f32(vals0[2 * d], vals0[2 * d + 1], 0, false);
                    u = (unsigned)__builtin_amdgcn_cvt_pk_fp8_f32(vals1[2 * d], vals1[2 * d + 1], (int)u, true);
                    pk[d] = u;
                }
                *(uint4*)(kv + obase) = make_uint4(pk[0], pk[1], pk[2], pk[3]);
                *(uint4*)(kv + obase + 4) = make_uint4(pk[4], pk[5], pk[6], pk[7]);
            }
        }
    }
}

// ---------------- per-node attention + beta-gate + GELU + LayerNorm ----------------
// 4 nodes per wave via LPT perm (degree-sorted desc): 16-lane group per node, lane owns 8 channels (1 uint4 kv).
// Unroll-2 + depth-2 prefetch (2 pairs in flight). Zero LDS.
// Algebra: logit = q·k + av*(q·we);  out = (Σw·v + (Σw·av)·we)/Σw. exp2-domain, defer-max.
// houtb may alias res32 (same-wave RAW only).
__global__ __launch_bounds__(256) void node_attn_fuse(const unsigned* __restrict__ q32,
                                                      const unsigned* __restrict__ kv, const unsigned* __restrict__ esrc,
                                                      const float* __restrict__ We, const int* __restrict__ row_ptr,
                                                      const int* __restrict__ perm, const unsigned* __restrict__ xr32,
                                                      const unsigned* res32, const float* __restrict__ Wb,
                                                      const float* __restrict__ lng, const float* __restrict__ lnb,
                                                      unsigned* houtb, float* houtf) {
    const int tid = threadIdx.x;
    const int lane = tid & 63;
    const int lnl = lane & 15;    // lane within node group
    const int gbase = lane & 48;  // group base lane
    const int node = perm[blockIdx.x * 16 + (tid >> 4)];  // LPT order; 50000 = 3125*16 exact
    const int base = row_ptr[node], end = row_ptr[node + 1];
    const float SC = 0.25505654047688565f;  // (1/sqrt(32)) * log2(e)
    const float THR = 8.0f;

    float qv[8], wev[8];
    {
        uint4 qw = *(const uint4*)(q32 + (size_t)node * 64 + 4 * lnl);
        unsigned qd[4] = {qw.x, qw.y, qw.z, qw.w};
#pragma unroll
        for (int t = 0; t < 4; ++t) {
            qv[2 * t] = bf2f((unsigned short)qd[t]) * SC;
            qv[2 * t + 1] = bf2f((unsigned short)(qd[t] >> 16)) * SC;
        }
        float4 wlo = *(const float4*)(We + 8 * lnl);
        float4 whi = *(const float4*)(We + 8 * lnl + 4);
        wev[0] = wlo.x; wev[1] = wlo.y; wev[2] = wlo.z; wev[3] = wlo.w;
        wev[4] = whi.x; wev[5] = whi.y; wev[6] = whi.z; wev[7] = whi.w;
    }
    float qwe;
    {
        float s = 0.f;
#pragma unroll
        for (int i = 0; i < 8; ++i) s = fmaf(qv[i], wev[i], s);
        s += dpp_xor1(s);
        s += dpp_xor2(s);
        qwe = s;
    }

    float m = -1e30f, sden = 0.f, tacc = 0.f;
    float acc[8] = {};
    const unsigned* kvp = kv + 4 * lnl;

    for (int off = 0; ; off += 16) {
        int cnt = min(end - base - off, 16);  // per-group; may be <= 0
        if (__all(cnt <= 0)) break;
        unsigned u_l = 0;
        if (lnl < cnt) u_l = esrc[base + off + lnl];
        int cm = max(cnt, 0);
        cm = max(cm, __shfl_xor(cm, 16));
        cm = max(cm, __shfl_xor(cm, 32));
        // depth-2: two pairs in flight (padding slots -> row 0, L2-hot)
        unsigned ue0 = (unsigned)__shfl((int)u_l, gbase + 0);
        unsigned ue1 = (unsigned)__shfl((int)u_l, gbase + 1);
        unsigned ue2 = (unsigned)__shfl((int)u_l, gbase + 2);
        unsigned ue3 = (unsigned)__shfl((int)u_l, gbase + 3);
        uint4 kw0 = *(const uint4*)(kvp + (size_t)(ue0 & 0xFFFFu) * 64);
        uint4 kw1 = *(const uint4*)(kvp + (size_t)(ue1 & 0xFFFFu) * 64);
        uint4 kw2 = *(const uint4*)(kvp + (size_t)(ue2 & 0xFFFFu) * 64);
        uint4 kw3 = *(const uint4*)(kvp + (size_t)(ue3 & 0xFFFFu) * 64);
        for (int j = 0; j < cm; j += 2) {
            uint4 ka = kw0, kb = kw1;
            unsigned ua = ue0, ub = ue1;
            // shift pipeline and issue next pair
            ue0 = ue2; ue1 = ue3; kw0 = kw2; kw1 = kw3;
            if (j + 4 < cm) {
                ue2 = (unsigned)__shfl((int)u_l, gbase + j + 4);
                ue3 = (unsigned)__shfl((int)u_l, gbase + j + 5);
                kw2 = *(const uint4*)(kvp + (size_t)(ue2 & 0xFFFFu) * 64);
                kw3 = *(const uint4*)(kvp + (size_t)(ue3 & 0xFFFFu) * 64);
            }
            float av0 = bf2f((unsigned short)(ua >> 16));
            float av1 = bf2f((unsigned short)(ub >> 16));
            unsigned kd0[4] = {ka.x, ka.y, ka.z, ka.w};
            unsigned kd1[4] = {kb.x, kb.y, kb.z, kb.w};
            float vj0[8], vj1[8];
            float p0 = 0.f, p1 = 0.f;
#pragma unroll
            for (int t = 0; t < 4; ++t) {
                f32x2 k0 = __builtin_amdgcn_cvt_pk_f32_fp8((int)kd0[t], false);
                f32x2 v0 = __builtin_amdgcn_cvt_pk_f32_fp8((int)kd0[t], true);
                f32x2 k1 = __builtin_amdgcn_cvt_pk_f32_fp8((int)kd1[t], false);
                f32x2 v1 = __builtin_amdgcn_cvt_pk_f32_fp8((int)kd1[t], true);
                p0 = fmaf(qv[2 * t], k0.x, p0);
                p0 = fmaf(qv[2 * t + 1], k0.y, p0);
                p1 = fmaf(qv[2 * t], k1.x, p1);
                p1 = fmaf(qv[2 * t + 1], k1.y, p1);
                vj0[2 * t] = v0.x; vj0[2 * t + 1] = v0.y;
                vj1[2 * t] = v1.x; vj1[2 * t + 1] = v1.y;
            }
            p0 += dpp_xor1(p0);
            p0 += dpp_xor2(p0);
            p1 += dpp_xor1(p1);
            p1 += dpp_xor2(p1);
            p0 = fmaf(av0, qwe, p0);
            p1 = fmaf(av1, qwe, p1);
            p0 = (j < cnt) ? p0 : -3e38f;
            p1 = (j + 1 < cnt) ? p1 : -3e38f;
            float pm = fmaxf(p0, p1);
            if (__any(pm - m > THR)) {  // rare: max update + rescale (taken on first pair)
                float mn2 = fmaxf(m, pm);
                float sc = exp2f(m - mn2);
                float w0 = exp2f(p0 - mn2), w1 = exp2f(p1 - mn2);
                sden = fmaf(sden, sc, w0 + w1);
                tacc = fmaf(tacc, sc, fmaf(w0, av0, w1 * av1));
#pragma unroll
                for (int i = 0; i < 8; ++i) acc[i] = fmaf(acc[i], sc, fmaf(w0, vj0[i], w1 * vj1[i]));
                m = mn2;
            } else {  // common path: independent exp2s, 2-deep fma tree
                float w0 = exp2f(p0 - m), w1 = exp2f(p1 - m);
                sden += w0 + w1;
                tacc = fmaf(w0, av0, fmaf(w1, av1, tacc));
#pragma unroll
                for (int i = 0; i < 8; ++i) acc[i] = fmaf(w0, vj0[i], fmaf(w1, vj1[i], acc[i]));
            }
        }
    }

    float rden = 1.f / (sden + 1e-16f);
    float o[8];
#pragma unroll
    for (int i = 0; i < 8; ++i) o[i] = fmaf(tacc, wev[i], acc[i]) * rden;

    // ---- fused epilogue in the same 8-ch/lane layout (reduces within 16-lane group) ----
    float x[8];
    {
        uint4 xw = *(const uint4*)(xr32 + (size_t)node * 64 + 4 * lnl);
        unsigned xd[4] = {xw.x, xw.y, xw.z, xw.w};
#pragma unroll
        for (int t = 0; t < 4; ++t) {
            x[2 * t] = bf2f((unsigned short)xd[t]);
            x[2 * t + 1] = bf2f((unsigned short)(xd[t] >> 16));
        }
    }
    float bl = 0.f;
#pragma unroll
    for (int t = 0; t < 2; ++t) {
        float4 w0 = *(const float4*)(Wb + 8 * lnl + 4 * t);
        float4 w1 = *(const float4*)(Wb + 128 + 8 * lnl + 4 * t);
        float4 w2 = *(const float4*)(Wb + 256 + 8 * lnl + 4 * t);
        bl = fmaf(o[4 * t], w0.x, bl); bl = fmaf(o[4 * t + 1], w0.y, bl);
        bl = fmaf(o[4 * t + 2], w0.z, bl); bl = fmaf(o[4 * t + 3], w0.w, bl);
        bl = fmaf(x[4 * t], w1.x, bl); bl = fmaf(x[4 * t + 1], w1.y, bl);
        bl = fmaf(x[4 * t + 2], w1.z, bl); bl = fmaf(x[4 * t + 3], w1.w, bl);
        bl = fmaf(o[4 * t] - x[4 * t], w2.x, bl); bl = fmaf(o[4 * t + 1] - x[4 * t + 1], w2.y, bl);
        bl = fmaf(o[4 * t + 2] - x[4 * t + 2], w2.z, bl); bl = fmaf(o[4 * t + 3] - x[4 * t + 3], w2.w, bl);
    }
    bl = red16(bl);
    float beta = 1.f / (1.f + __expf(-bl));
    float tpre[8];
    {
        uint4 rw = *(const uint4*)(res32 + (size_t)node * 64 + 4 * lnl);
        unsigned rd[4] = {rw.x, rw.y, rw.z, rw.w};
#pragma unroll
        for (int i = 0; i < 8; ++i) {
            float gg = beta * x[i] + (1.f - beta) * o[i];
            gg = 0.5f * gg * (1.f + erff(gg * 0.70710678118654752f));
            float rv = (i & 1) ? bf2f((unsigned short)(rd[i >> 1] >> 16)) : bf2f((unsigned short)rd[i >> 1]);
            tpre[i] = gg + rv;
        }
    }
    float su = 0.f, sq = 0.f;
#pragma unroll
    for (int i = 0; i < 8; ++i) {
        su += tpre[i];
        sq = fmaf(tpre[i], tpre[i], sq);
    }
    su = red16(su);
    sq = red16(sq);
    float mu = su * (1.f / 128.f);
    float var = sq * (1.f / 128.f) - mu * mu;
    float inv = rsqrtf(var + 1e-5f);
    float4 g0 = *(const float4*)(lng + 8 * lnl);
    float4 g1 = *(const float4*)(lng + 8 * lnl + 4);
    float4 b0 = *(const float4*)(lnb + 8 * lnl);
    float4 b1 = *(const float4*)(lnb + 8 * lnl + 4);
    float gg[8] = {g0.x, g0.y, g0.z, g0.w, g1.x, g1.y, g1.z, g1.w};
    float bb[8] = {b0.x, b0.y, b0.z, b0.w, b1.x, b1.y, b1.z, b1.w};
    float ov[8];
#pragma unroll
    for (int i = 0; i < 8; ++i) ov[i] = (tpre[i] - mu) * inv * gg[i] + bb[i];
    if (houtf) {
        float* op = houtf + (size_t)node * 128 + 8 * lnl;
        *(float4*)op = make_float4(ov[0], ov[1], ov[2], ov[3]);
        *(float4*)(op + 4) = make_float4(ov[4], ov[5], ov[6], ov[7]);
    } else {
        unsigned pk[4];
#pragma unroll
        for (int d = 0; d < 4; ++d) pk[d] = packbf(ov[2 * d], ov[2 * d + 1]);
        *(uint4*)(houtb + (size_t)node * 64 + 4 * lnl) = make_uint4(pk[0], pk[1], pk[2], pk[3]);
    }
}

extern "C" void kernel_launch(void* const* d_in, const int* in_sizes, int n_in, void* d_out, int out_size,
                              void* d_ws, size_t ws_size, hipStream_t stream) {
    const float* x = (const float*)d_in[0];
    const int* ei = (const int*)d_in[1];
    const float* ea = (const float*)d_in[2];
    const float* Wi = (const float*)d_in[3];
    const float* bi = (const float*)d_in[4];
    const float* Wq = (const float*)d_in[5];
    const float* bq = (const float*)d_in[6];
    const float* Wk = (const float*)d_in[7];
    const float* bk = (const float*)d_in[8];
    const float* Wv = (const float*)d_in[9];
    const float* bv = (const float*)d_in[10];
    const float* We = (const float*)d_in[11];
    const float* Wskip = (const float*)d_in[12];
    const float* bskip = (const float*)d_in[13];
    const float* Wbeta = (const float*)d_in[14];
    const float* lng = (const float*)d_in[15];
    const float* lnb = (const float*)d_in[16];

    const int* srcp = ei;
    const int* dstp = ei + NEDGES;

    char* p = (char*)d_ws;
    auto alloc = [&](size_t bytes) {
        void* r = (void*)p;
        p += (bytes + 255) & ~(size_t)255;
        return r;
    };
    unsigned* h32 = (unsigned*)alloc((size_t)NNODES * 64 * 4);
    unsigned* q32 = (unsigned*)alloc((size_t)NNODES * 64 * 4);
    unsigned* xr32 = (unsigned*)alloc((size_t)NNODES * 64 * 4);
    unsigned* kv = (unsigned*)alloc((size_t)NNODES * 64 * 4);
    unsigned short* Wit = (unsigned short*)alloc((size_t)DHID * DIN * 2);
    unsigned short* Wt3 = (unsigned short*)alloc((size_t)3 * 512 * DHID * 2);
    int* counts = (int*)alloc((size_t)(NNODES + 768) * 4);  // counts + bfill(256) + dh(256) + dfill(256), one memset
    int* bfill = counts + NNODES;
    int* dh = bfill + 256;
    int* dfill = dh + 256;
    int* dbase = (int*)alloc(256 * 4);
    int* perm = (int*)alloc((size_t)NNODES * 4);
    int* row_ptr = (int*)alloc((size_t)(NNODES + 1) * 4);
    unsigned* esrc = (unsigned*)alloc((size_t)NEDGES * 4);
    unsigned* brec = (unsigned*)alloc((size_t)NEDGES * 4);
    unsigned char* bdst = (unsigned char*)alloc((size_t)NEDGES);
    int* partials = (int*)alloc(256 * 4);

    const int EB = (NEDGES + 255) / 256;  // 3125
    const int NB = (NNODES + 255) / 256;  // 196
    const int WB = NNODES / 16;           // 3125
    const int PB = (DHID * DIN + 3 * 512 * DHID + 255) / 256;  // 896
    const int AB = (NEDGES + CHUNK - 1) / CHUNK;  // 196

    hipMemsetAsync(counts, 0, (size_t)(NNODES + 768) * 4, stream);
    prep_hist<<<PB + EB, 256, 0, stream>>>(Wi, Wq, Wk, Wv, Wskip, Wit, Wt3, dstp, counts, PB);
    gemm_in<<<GBLK, 256, 0, stream>>>(x, Wit, bi, h32, NNODES);
    k_scan_block<<<NB, 256, 0, stream>>>(counts, row_ptr + 1, partials, NNODES, dh);
    k_apply2<<<NB, 256, 0, stream>>>(partials, row_ptr, NNODES, NB, dh, dbase);
    perm_scatter<<<NB, 256, 0, stream>>>(counts, dbase, dfill, perm);
    bin_edges<<<AB, 256, 0, stream>>>(srcp, dstp, ea, row_ptr, bfill, brec, bdst);
    sort_bucket<<<NBUCK, 256, 0, stream>>>(brec, bdst, row_ptr, esrc);

    for (int l = 0; l < 3; ++l) {
        const size_t bo = (size_t)l * 128;
        gemm_qkvs<<<QBLK, 256, 0, stream>>>((const unsigned short*)h32, Wt3 + (size_t)l * 512 * DHID, bq + bo, bk + bo,
                                            bv + bo, bskip + bo, q32, kv, xr32, NNODES);
        node_attn_fuse<<<WB, 256, 0, stream>>>(q32, kv, esrc, We + bo, row_ptr, perm, xr32, h32,
                                               Wbeta + (size_t)l * 384, lng + bo, lnb + bo, h32,
                                               (l == 2) ? (float*)d_out : nullptr);
    }
}

// Round 14
// 324.208 us; speedup vs baseline: 1.0001x; 1.0001x over previous
//
#include <hip/hip_runtime.h>
#include <math.h>

#define NNODES 50000
#define NEDGES 800000
#define DIN 256
#define DHID 128
#define GBLK 391   // gemm_in row blocks = ceil(50000/128)
#define QBLK 782   // gemm_qkvs row blocks = ceil(50000/64)
#define NBUCK 196  // ceil(50000/256) dst buckets
#define CHUNK 4096 // edges per bin_edges block

typedef __attribute__((ext_vector_type(8))) short short8;
typedef __attribute__((ext_vector_type(4))) float f32x4;
typedef __attribute__((ext_vector_type(2))) float f32x2;

__device__ __forceinline__ unsigned short f2bf(float f) {
    unsigned u = __builtin_bit_cast(unsigned, f);
    u += 0x7fffu + ((u >> 16) & 1u);  // RNE
    return (unsigned short)(u >> 16);
}
__device__ __forceinline__ float bf2f(unsigned short s) {
    return __builtin_bit_cast(float, (unsigned)s << 16);
}
__device__ __forceinline__ unsigned packbf(float a, float b) {
    return (unsigned)f2bf(a) | ((unsigned)f2bf(b) << 16);
}
// DPP helpers: full-rate VALU cross-lane (no LDS)
__device__ __forceinline__ float dpp_xor1(float x) {  // quad_perm [1,0,3,2]
    return __builtin_bit_cast(float, __builtin_amdgcn_update_dpp(0, __builtin_bit_cast(int, x), 0xB1, 0xF, 0xF, true));
}
__device__ __forceinline__ float dpp_xor2(float x) {  // quad_perm [2,3,0,1]
    return __builtin_bit_cast(float, __builtin_amdgcn_update_dpp(0, __builtin_bit_cast(int, x), 0x4E, 0xF, 0xF, true));
}
__device__ __forceinline__ float dpp_hmirror(float x) {  // row_half_mirror
    return __builtin_bit_cast(float, __builtin_amdgcn_update_dpp(0, __builtin_bit_cast(int, x), 0x141, 0xF, 0xF, true));
}
__device__ __forceinline__ float dpp_mirror(float x) {  // row_mirror
    return __builtin_bit_cast(float, __builtin_amdgcn_update_dpp(0, __builtin_bit_cast(int, x), 0x140, 0xF, 0xF, true));
}
__device__ __forceinline__ float red16(float x) {
    x += dpp_xor1(x);
    x += dpp_xor2(x);
    x += dpp_hmirror(x);
    x += dpp_mirror(x);
    return x;
}

// ---------------- weight prep (blocks < pb) + degree histogram (blocks >= pb) ----------------
__global__ __launch_bounds__(256) void prep_hist(const float* __restrict__ Wi, const float* __restrict__ Wq,
                                                 const float* __restrict__ Wk, const float* __restrict__ Wv,
                                                 const float* __restrict__ Ws, unsigned short* __restrict__ Wit,
                                                 unsigned short* __restrict__ Wt3, const int* __restrict__ dst,
                                                 int* __restrict__ counts, int pb) {
    if ((int)blockIdx.x < pb) {
        int idx = blockIdx.x * 256 + threadIdx.x;
        if (idx < DHID * DIN) {
            int n = idx >> 8, kk = idx & 255;
            Wit[idx] = f2bf(Wi[kk * DHID + n]);
        }
        int idx2 = idx - DHID * DIN;
        if (idx2 >= 0 && idx2 < 3 * 512 * DHID) {
            int l = idx2 / (512 * DHID);
            int rem = idx2 - l * 512 * DHID;
            int r = rem >> 7;
            int kk = rem & 127;
            int sel = r >> 7, rl = r & 127;
            const float* srcm = sel == 0 ? Wq : sel == 1 ? Wk : sel == 2 ? Wv : Ws;
            Wt3[idx2] = f2bf(srcm[l * DHID * DHID + kk * DHID + rl]);
        }
    } else {
        int e = (blockIdx.x - pb) * 256 + threadIdx.x;
        if (e < NEDGES) atomicAdd(&counts[dst[e]], 1);
    }
}

// scan counts -> row_ptr+1 partials; ALSO accumulate degree histogram (deg clamp 255) into dh
__global__ __launch_bounds__(256) void k_scan_block(const int* __restrict__ in, int* __restrict__ out,
                                                    int* __restrict__ partials, int n, int* __restrict__ dh) {
    __shared__ int sh[256];
    __shared__ int dhist[256];
    int tid = threadIdx.x;
    int i = blockIdx.x * 256 + tid;
    int vv = (i < n) ? in[i] : 0;
    sh[tid] = vv;
    dhist[tid] = 0;
    __syncthreads();
    if (i < n) atomicAdd(&dhist[min(vv, 255)], 1);
    for (int off = 1; off < 256; off <<= 1) {
        int t = (tid >= off) ? sh[tid - off] : 0;
        __syncthreads();
        sh[tid] += t;
        __syncthreads();
    }
    if (i < n) out[i] = sh[tid];
    if (tid == 255) partials[blockIdx.x] = sh[255];
    __syncthreads();
    int hc = dhist[tid];
    if (hc) atomicAdd(&dh[tid], hc);
}

// apply block prefixes to row_ptr; block 0 also builds dbase = descending-degree exclusive prefix of dh
__global__ __launch_bounds__(256) void k_apply2(const int* __restrict__ partials, int* __restrict__ row_ptr, int n,
                                                int nb, const int* __restrict__ dh, int* __restrict__ dbase) {
    __shared__ int sh[256];
    int tid = threadIdx.x;
    int vv = (tid < nb) ? partials[tid] : 0;
    sh[tid] = vv;
    __syncthreads();
    for (int off = 1; off < 256; off <<= 1) {
        int t = (tid >= off) ? sh[tid - off] : 0;
        __syncthreads();
        sh[tid] += t;
        __syncthreads();
    }
    int i = blockIdx.x * 256 + tid;
    if (i < n) {
        int add = blockIdx.x ? sh[blockIdx.x - 1] : 0;
        row_ptr[i + 1] += add;
    }
    if (i == 0) row_ptr[0] = 0;
    if (blockIdx.x == 0) {
        __syncthreads();
        int c = dh[255 - tid];
        sh[tid] = c;
        __syncthreads();
        for (int off = 1; off < 256; off <<= 1) {
            int t = (tid >= off) ? sh[tid - off] : 0;
            __syncthreads();
            sh[tid] += t;
            __syncthreads();
        }
        dbase[255 - tid] = sh[tid] - c;  // exclusive prefix, highest degree first
    }
}

// LPT permutation: perm = node ids sorted by degree descending (LDS-aggregated counting sort)
__global__ __launch_bounds__(256) void perm_scatter(const int* __restrict__ counts, const int* __restrict__ dbase,
                                                    int* __restrict__ dfill, int* __restrict__ perm) {
    __shared__ int h[256], gb[256], c2[256];
    const int tid = threadIdx.x;
    int i = blockIdx.x * 256 + tid;
    int d = (i < NNODES) ? min(counts[i], 255) : -1;
    h[tid] = 0;
    c2[tid] = 0;
    __syncthreads();
    if (d >= 0) atomicAdd(&h[d], 1);
    __syncthreads();
    int c = h[tid];
    gb[tid] = c ? dbase[tid] + atomicAdd(&dfill[tid], c) : 0;
    __syncthreads();
    if (d >= 0) {
        int r = atomicAdd(&c2[d], 1);
        perm[gb[d] + r] = i;
    }
}

// ---------------- pass A: bin edges by dst>>8 into bucket-grouped intermediate (coalesced writes) ----------------
__global__ __launch_bounds__(256) void bin_edges(const int* __restrict__ src, const int* __restrict__ dst,
                                                 const float* __restrict__ ea, const int* __restrict__ row_ptr,
                                                 int* __restrict__ bfill, unsigned* __restrict__ brec,
                                                 unsigned char* __restrict__ bdst) {
    __shared__ int hist[NBUCK];
    __shared__ int lbase[NBUCK];
    __shared__ int gbase[NBUCK];
    __shared__ int cnt[NBUCK];
    __shared__ unsigned rec4[CHUNK];
    __shared__ unsigned char dl8[CHUNK];
    __shared__ unsigned char bk8[CHUNK];
    const int tid = threadIdx.x;
    const int e0 = blockIdx.x * CHUNK;
    const int n = min(NEDGES - e0, CHUNK);
    for (int i = tid; i < NBUCK; i += 256) hist[i] = 0;
    __syncthreads();
    for (int i = tid; i < n; i += 256) atomicAdd(&hist[dst[e0 + i] >> 8], 1);
    __syncthreads();
    if (tid == 0) {
        int run = 0;
        for (int b = 0; b < NBUCK; ++b) {
            lbase[b] = run;
            run += hist[b];
        }
    }
    __syncthreads();
    for (int b = tid; b < NBUCK; b += 256) {
        int h = hist[b];
        int off = h ? atomicAdd(&bfill[b], h) : 0;
        gbase[b] = row_ptr[b << 8] + off;
        cnt[b] = lbase[b];
    }
    __syncthreads();
    for (int i = tid; i < n; i += 256) {
        int d = dst[e0 + i];
        int b = d >> 8;
        int lp = atomicAdd(&cnt[b], 1);
        rec4[lp] = (unsigned)src[e0 + i] | ((unsigned)f2bf(ea[e0 + i]) << 16);
        dl8[lp] = (unsigned char)(d & 255);
        bk8[lp] = (unsigned char)b;
    }
    __syncthreads();
    for (int i = tid; i < n; i += 256) {
        int b = bk8[i];
        int pos = gbase[b] + (i - lbase[b]);
        brec[pos] = rec4[i];
        bdst[pos] = dl8[i];
    }
}

// ---------------- pass B: within-bucket counting sort; all stores confined to one block's window ----------------
__global__ __launch_bounds__(256) void sort_bucket(const unsigned* __restrict__ brec,
                                                   const unsigned char* __restrict__ bdst,
                                                   const int* __restrict__ row_ptr, unsigned* __restrict__ esrc) {
    __shared__ int rp[257];
    __shared__ int cnt[256];
    const int b = blockIdx.x;
    const int d0 = b << 8;
    const int nmax = min(256, NNODES - d0);
    const int tid = threadIdx.x;
    for (int i = tid; i <= nmax; i += 256) rp[i] = row_ptr[d0 + i];
    cnt[tid] = 0;
    __syncthreads();
    const int base = rp[0], end = rp[nmax];
    for (int i = base + tid; i < end; i += 256) {
        unsigned rec = brec[i];
        int d = bdst[i];
        int rank = atomicAdd(&cnt[d], 1);
        esrc[rp[d] + rank] = rec;
    }
}

// ---------------- input projection: h[M,128](bf16) = x[M,256] @ Wi + bi ----------------
__global__ __launch_bounds__(256) void gemm_in(const float* __restrict__ A, const unsigned short* __restrict__ Wt,
                                               const float* __restrict__ bias, unsigned* __restrict__ h32, int M) {
    __shared__ short As[128 * 128];
    const int tid = threadIdx.x;
    const int lane = tid & 63;
    const int wid = tid >> 6;
    const int row0 = blockIdx.x * 128;
    const int wr = (wid & 1) * 64;
    const int wc = (wid >> 1) * 64;
    f32x4 acc[4][4] = {};
    const int srow = tid >> 1;
    const int sk = (tid & 1) * 64;
    const int grow = min(row0 + srow, M - 1);
    for (int kt = 0; kt < 2; ++kt) {
        const float* ap = A + (size_t)grow * DIN + kt * 128 + sk;
#pragma unroll
        for (int i = 0; i < 8; ++i) {
            float4 f0 = *(const float4*)(ap + i * 8);
            float4 f1 = *(const float4*)(ap + i * 8 + 4);
            short8 s;
            s[0] = f2bf(f0.x); s[1] = f2bf(f0.y); s[2] = f2bf(f0.z); s[3] = f2bf(f0.w);
            s[4] = f2bf(f1.x); s[5] = f2bf(f1.y); s[6] = f2bf(f1.z); s[7] = f2bf(f1.w);
            int g = (sk >> 3) + i;
            *(short8*)(&As[srow * 128 + ((g ^ (srow & 7)) << 3)]) = s;
        }
        __syncthreads();
#pragma unroll
        for (int ks = 0; ks < 4; ++ks) {
            short8 a[4], b[4];
#pragma unroll
            for (int m = 0; m < 4; ++m) {
                int r = wr + m * 16 + (lane & 15);
                int g = ks * 4 + (lane >> 4);
                a[m] = *(const short8*)(&As[r * 128 + ((g ^ (r & 7)) << 3)]);
            }
#pragma unroll
            for (int n = 0; n < 4; ++n) {
                int c = wc + n * 16 + (lane & 15);
                b[n] = *(const short8*)(Wt + (size_t)c * DIN + kt * 128 + ks * 32 + (lane >> 4) * 8);
            }
#pragma unroll
            for (int m = 0; m < 4; ++m)
#pragma unroll
                for (int n = 0; n < 4; ++n)
                    acc[m][n] = __builtin_amdgcn_mfma_f32_16x16x32_bf16(a[m], b[n], acc[m][n], 0, 0, 0);
        }
        __syncthreads();
    }
    // epilogue: per-wave LDS repack (reuse As) -> coalesced uint4 stores
    float* my = ((float*)As) + wid * 1024;
    float bb[4];
#pragma unroll
    for (int n = 0; n < 4; ++n) bb[n] = bias[wc + n * 16 + (lane & 15)];
    const int rr = lane >> 2;
    const int cb = lane & 3;
#pragma unroll
    for (int m = 0; m < 4; ++m) {
#pragma unroll
        for (int n = 0; n < 4; ++n) {
            int lc = n * 16 + (lane & 15);
#pragma unroll
            for (int j = 0; j < 4; ++j) {
                int row = (lane >> 4) * 4 + j;
                my[row * 64 + (((lc >> 2) ^ (row & 7)) << 2) + (lc & 3)] = acc[m][n][j] + bb[n];
            }
        }
        float vals[16];
#pragma unroll
        for (int s = 0; s < 4; ++s) {
            int gx = (cb * 4 + s) ^ (rr & 7);
            f32x4 t4 = *(const f32x4*)(my + rr * 64 + gx * 4);
            vals[s * 4 + 0] = t4.x; vals[s * 4 + 1] = t4.y; vals[s * 4 + 2] = t4.z; vals[s * 4 + 3] = t4.w;
        }
        int grow2 = row0 + wr + m * 16 + rr;
        if (grow2 < M) {
            unsigned pk[8];
#pragma unroll
            for (int d = 0; d < 8; ++d) pk[d] = packbf(vals[2 * d], vals[2 * d + 1]);
            unsigned* op = h32 + (size_t)grow2 * 64 + (wc >> 1) + cb * 8;
            *(uint4*)op = make_uint4(pk[0], pk[1], pk[2], pk[3]);
            *(uint4*)(op + 4) = make_uint4(pk[4], pk[5], pk[6], pk[7]);
        }
    }
}

// ---------------- fused q/k/v/skip GEMM from bf16 h: 64-row blocks, 4 waves (balanced packing) ----------------
__global__ __launch_bounds__(256) void gemm_qkvs(const unsigned short* __restrict__ A,
                                                 const unsigned short* __restrict__ Wt, const float* __restrict__ bq,
                                                 const float* __restrict__ bk, const float* __restrict__ bv,
                                                 const float* __restrict__ bs, unsigned* __restrict__ q32,
                                                 unsigned* __restrict__ kv, unsigned* __restrict__ xr32, int M) {
    __shared__ short As[64 * 128];  // 16 KB
    const int tid = threadIdx.x;
    const int lane = tid & 63;
    const int wid = tid >> 6;  // 0..3
    const int row0 = blockIdx.x * 64;
    const int sel = wid >> 1;        // 0: q/skip, 1: k/v
    const int wc = (wid & 1) * 64;   // col half within the pair's 128 cols
    f32x4 acc0[4][4] = {}, acc1[4][4] = {};
    {
        const int srow = tid >> 2;        // 0..63
        const int sk = (tid & 3) * 32;
        const int grow = min(row0 + srow, M - 1);
        const unsigned short* ap = A + (size_t)grow * DHID + sk;
#pragma unroll
        for (int i = 0; i < 4; ++i) {
            short8 s = *(const short8*)(ap + i * 8);
            int g = (sk >> 3) + i;
            *(short8*)(&As[srow * 128 + ((g ^ (srow & 7)) << 3)]) = s;
        }
    }
    __syncthreads();
    const int b0base = sel ? 128 : 0;    // k : q
    const int b1base = sel ? 256 : 384;  // v : skip
#pragma unroll
    for (int ks = 0; ks < 4; ++ks) {
        short8 a[4], b0[4], b1[4];
#pragma unroll
        for (int m = 0; m < 4; ++m) {
            int r = m * 16 + (lane & 15);
            int g = ks * 4 + (lane >> 4);
            a[m] = *(const short8*)(&As[r * 128 + ((g ^ (r & 7)) << 3)]);
        }
#pragma unroll
        for (int n = 0; n < 4; ++n) {
            int rb = wc + n * 16 + (lane & 15);
            b0[n] = *(const short8*)(Wt + (size_t)(b0base + rb) * DHID + ks * 32 + (lane >> 4) * 8);
            b1[n] = *(const short8*)(Wt + (size_t)(b1base + rb) * DHID + ks * 32 + (lane >> 4) * 8);
        }
#pragma unroll
        for (int m = 0; m < 4; ++m)
#pragma unroll
            for (int n = 0; n < 4; ++n) {
                acc0[m][n] = __builtin_amdgcn_mfma_f32_16x16x32_bf16(a[m], b0[n], acc0[m][n], 0, 0, 0);
                acc1[m][n] = __builtin_amdgcn_mfma_f32_16x16x32_bf16(a[m], b1[n], acc1[m][n], 0, 0, 0);
            }
    }
    __syncthreads();  // done reading As; reuse as repack buffer (4 waves x 4 KB = 16 KB)
    float* my = ((float*)As) + wid * 1024;
    const float* bias0 = sel ? bk : bq;
    const float* bias1 = sel ? bv : bs;
    float bb0[4], bb1[4];
#pragma unroll
    for (int n = 0; n < 4; ++n) {
        int c = wc + n * 16 + (lane & 15);
        bb0[n] = bias0[c];
        bb1[n] = bias1[c];
    }
    const int rr = lane >> 2;
    const int cb = lane & 3;
#pragma unroll
    for (int m = 0; m < 4; ++m) {
        float vals0[16], vals1[16];
#pragma unroll
        for (int n = 0; n < 4; ++n) {
            int lc = n * 16 + (lane & 15);
#pragma unroll
            for (int j = 0; j < 4; ++j) {
                int row = (lane >> 4) * 4 + j;
                my[row * 64 + (((lc >> 2) ^ (row & 7)) << 2) + (lc & 3)] = acc0[m][n][j] + bb0[n];
            }
        }
#pragma unroll
        for (int s = 0; s < 4; ++s) {
            int gx = (cb * 4 + s) ^ (rr & 7);
            f32x4 t4 = *(const f32x4*)(my + rr * 64 + gx * 4);
            vals0[s * 4 + 0] = t4.x; vals0[s * 4 + 1] = t4.y; vals0[s * 4 + 2] = t4.z; vals0[s * 4 + 3] = t4.w;
        }
#pragma unroll
        for (int n = 0; n < 4; ++n) {
            int lc = n * 16 + (lane & 15);
#pragma unroll
            for (int j = 0; j < 4; ++j) {
                int row = (lane >> 4) * 4 + j;
                my[row * 64 + (((lc >> 2) ^ (row & 7)) << 2) + (lc & 3)] = acc1[m][n][j] + bb1[n];
            }
        }
#pragma unroll
        for (int s = 0; s < 4; ++s) {
            int gx = (cb * 4 + s) ^ (rr & 7);
            f32x4 t4 = *(const f32x4*)(my + rr * 64 + gx * 4);
            vals1[s * 4 + 0] = t4.x; vals1[s * 4 + 1] = t4.y; vals1[s * 4 + 2] = t4.z; vals1[s * 4 + 3] = t4.w;
        }
        int grow2 = row0 + m * 16 + rr;
        if (grow2 < M) {
            size_t obase = (size_t)grow2 * 64 + (wc >> 1) + cb * 8;
            if (sel == 0) {
                unsigned p0[8], p1[8];
#pragma unroll
                for (int d = 0; d < 8; ++d) {
                    p0[d] = packbf(vals0[2 * d], vals0[2 * d + 1]);
                    p1[d] = packbf(vals1[2 * d], vals1[2 * d + 1]);
                }
                *(uint4*)(q32 + obase) = make_uint4(p0[0], p0[1], p0[2], p0[3]);
                *(uint4*)(q32 + obase + 4) = make_uint4(p0[4], p0[5], p0[6], p0[7]);
                *(uint4*)(xr32 + obase) = make_uint4(p1[0], p1[1], p1[2], p1[3]);
                *(uint4*)(xr32 + obase + 4) = make_uint4(p1[4], p1[5], p1[6], p1[7]);
            } else {
                unsigned pk[8];
#pragma unroll
                for (int d = 0; d < 8; ++d) {
                    unsigned u = (unsigned)__builtin_amdgcn_cvt_pk_fp8_f32(vals0[2 * d], vals0[2 * d + 1], 0, false);
                    u = (unsigned)__builtin_amdgcn_cvt_pk_fp8_f32(vals1[2 * d], vals1[2 * d + 1], (int)u, true);
                    pk[d] = u;
                }
                *(uint4*)(kv + obase) = make_uint4(pk[0], pk[1], pk[2], pk[3]);
                *(uint4*)(kv + obase + 4) = make_uint4(pk[4], pk[5], pk[6], pk[7]);
            }
        }
    }
}

// ---------------- per-node attention + beta-gate + GELU + LayerNorm ----------------
// 4 nodes per wave via LPT perm (degree-sorted desc): 16-lane group per node, lane owns 8 channels (1 uint4 kv).
// Unroll-2 + depth-2 prefetch (2 pairs in flight). Zero LDS.
// Algebra: logit = q·k + av*(q·we);  out = (Σw·v + (Σw·av)·we)/Σw. exp2-domain, defer-max.
// houtb may alias res32 (same-wave RAW only).
__global__ __launch_bounds__(256) void node_attn_fuse(const unsigned* __restrict__ q32,
                                                      const unsigned* __restrict__ kv, const unsigned* __restrict__ esrc,
                                                      const float* __restrict__ We, const int* __restrict__ row_ptr,
                                                      const int* __restrict__ perm, const unsigned* __restrict__ xr32,
                                                      const unsigned* res32, const float* __restrict__ Wb,
                                                      const float* __restrict__ lng, const float* __restrict__ lnb,
                                                      unsigned* houtb, float* houtf) {
    const int tid = threadIdx.x;
    const int lane = tid & 63;
    const int lnl = lane & 15;    // lane within node group
    const int gbase = lane & 48;  // group base lane
    const int node = perm[blockIdx.x * 16 + (tid >> 4)];  // LPT order; 50000 = 3125*16 exact
    const int base = row_ptr[node], end = row_ptr[node + 1];
    const float SC = 0.25505654047688565f;  // (1/sqrt(32)) * log2(e)
    const float THR = 8.0f;

    float qv[8], wev[8];
    {
        uint4 qw = *(const uint4*)(q32 + (size_t)node * 64 + 4 * lnl);
        unsigned qd[4] = {qw.x, qw.y, qw.z, qw.w};
#pragma unroll
        for (int t = 0; t < 4; ++t) {
            qv[2 * t] = bf2f((unsigned short)qd[t]) * SC;
            qv[2 * t + 1] = bf2f((unsigned short)(qd[t] >> 16)) * SC;
        }
        float4 wlo = *(const float4*)(We + 8 * lnl);
        float4 whi = *(const float4*)(We + 8 * lnl + 4);
        wev[0] = wlo.x; wev[1] = wlo.y; wev[2] = wlo.z; wev[3] = wlo.w;
        wev[4] = whi.x; wev[5] = whi.y; wev[6] = whi.z; wev[7] = whi.w;
    }
    float qwe;
    {
        float s = 0.f;
#pragma unroll
        for (int i = 0; i < 8; ++i) s = fmaf(qv[i], wev[i], s);
        s += dpp_xor1(s);
        s += dpp_xor2(s);
        qwe = s;
    }

    float m = -1e30f, sden = 0.f, tacc = 0.f;
    float acc[8] = {};
    const unsigned* kvp = kv + 4 * lnl;

    for (int off = 0; ; off += 16) {
        int cnt = min(end - base - off, 16);  // per-group; may be <= 0
        if (__all(cnt <= 0)) break;
        unsigned u_l = 0;
        if (lnl < cnt) u_l = esrc[base + off + lnl];
        int cm = max(cnt, 0);
        cm = max(cm, __shfl_xor(cm, 16));
        cm = max(cm, __shfl_xor(cm, 32));
        // depth-2: two pairs in flight (padding slots -> row 0, L2-hot)
        unsigned ue0 = (unsigned)__shfl((int)u_l, gbase + 0);
        unsigned ue1 = (unsigned)__shfl((int)u_l, gbase + 1);
        unsigned ue2 = (unsigned)__shfl((int)u_l, gbase + 2);
        unsigned ue3 = (unsigned)__shfl((int)u_l, gbase + 3);
        uint4 kw0 = *(const uint4*)(kvp + (size_t)(ue0 & 0xFFFFu) * 64);
        uint4 kw1 = *(const uint4*)(kvp + (size_t)(ue1 & 0xFFFFu) * 64);
        uint4 kw2 = *(const uint4*)(kvp + (size_t)(ue2 & 0xFFFFu) * 64);
        uint4 kw3 = *(const uint4*)(kvp + (size_t)(ue3 & 0xFFFFu) * 64);
        for (int j = 0; j < cm; j += 2) {
            uint4 ka = kw0, kb = kw1;
            unsigned ua = ue0, ub = ue1;
            // shift pipeline and issue next pair
            ue0 = ue2; ue1 = ue3; kw0 = kw2; kw1 = kw3;
            if (j + 4 < cm) {
                ue2 = (unsigned)__shfl((int)u_l, gbase + j + 4);
                ue3 = (unsigned)__shfl((int)u_l, gbase + j + 5);
                kw2 = *(const uint4*)(kvp + (size_t)(ue2 & 0xFFFFu) * 64);
                kw3 = *(const uint4*)(kvp + (size_t)(ue3 & 0xFFFFu) * 64);
            }
            float av0 = bf2f((unsigned short)(ua >> 16));
            float av1 = bf2f((unsigned short)(ub >> 16));
            unsigned kd0[4] = {ka.x, ka.y, ka.z, ka.w};
            unsigned kd1[4] = {kb.x, kb.y, kb.z, kb.w};
            float vj0[8], vj1[8];
            float p0 = 0.f, p1 = 0.f;
#pragma unroll
            for (int t = 0; t < 4; ++t) {
                f32x2 k0 = __builtin_amdgcn_cvt_pk_f32_fp8((int)kd0[t], false);
                f32x2 v0 = __builtin_amdgcn_cvt_pk_f32_fp8((int)kd0[t], true);
                f32x2 k1 = __builtin_amdgcn_cvt_pk_f32_fp8((int)kd1[t], false);
                f32x2 v1 = __builtin_amdgcn_cvt_pk_f32_fp8((int)kd1[t], true);
                p0 = fmaf(qv[2 * t], k0.x, p0);
                p0 = fmaf(qv[2 * t + 1], k0.y, p0);
                p1 = fmaf(qv[2 * t], k1.x, p1);
                p1 = fmaf(qv[2 * t + 1], k1.y, p1);
                vj0[2 * t] = v0.x; vj0[2 * t + 1] = v0.y;
                vj1[2 * t] = v1.x; vj1[2 * t + 1] = v1.y;
            }
            p0 += dpp_xor1(p0);
            p0 += dpp_xor2(p0);
            p1 += dpp_xor1(p1);
            p1 += dpp_xor2(p1);
            p0 = fmaf(av0, qwe, p0);
            p1 = fmaf(av1, qwe, p1);
            p0 = (j < cnt) ? p0 : -3e38f;
            p1 = (j + 1 < cnt) ? p1 : -3e38f;
            float pm = fmaxf(p0, p1);
            if (__any(pm - m > THR)) {  // rare: max update + rescale (taken on first pair)
                float mn2 = fmaxf(m, pm);
                float sc = exp2f(m - mn2);
                float w0 = exp2f(p0 - mn2), w1 = exp2f(p1 - mn2);
                sden = fmaf(sden, sc, w0 + w1);
                tacc = fmaf(tacc, sc, fmaf(w0, av0, w1 * av1));
#pragma unroll
                for (int i = 0; i < 8; ++i) acc[i] = fmaf(acc[i], sc, fmaf(w0, vj0[i], w1 * vj1[i]));
                m = mn2;
            } else {  // common path: independent exp2s, 2-deep fma tree
                float w0 = exp2f(p0 - m), w1 = exp2f(p1 - m);
                sden += w0 + w1;
                tacc = fmaf(w0, av0, fmaf(w1, av1, tacc));
#pragma unroll
                for (int i = 0; i < 8; ++i) acc[i] = fmaf(w0, vj0[i], fmaf(w1, vj1[i], acc[i]));
            }
        }
    }

    float rden = 1.f / (sden + 1e-16f);
    float o[8];
#pragma unroll
    for (int i = 0; i < 8; ++i) o[i] = fmaf(tacc, wev[i], acc[i]) * rden;

    // ---- fused epilogue in the same 8-ch/lane layout (reduces within 16-lane group) ----
    float x[8];
    {
        uint4 xw = *(const uint4*)(xr32 + (size_t)node * 64 + 4 * lnl);
        unsigned xd[4] = {xw.x, xw.y, xw.z, xw.w};
#pragma unroll
        for (int t = 0; t < 4; ++t) {
            x[2 * t] = bf2f((unsigned short)xd[t]);
            x[2 * t + 1] = bf2f((unsigned short)(xd[t] >> 16));
        }
    }
    float bl = 0.f;
#pragma unroll
    for (int t = 0; t < 2; ++t) {
        float4 w0 = *(const float4*)(Wb + 8 * lnl + 4 * t);
        float4 w1 = *(const float4*)(Wb + 128 + 8 * lnl + 4 * t);
        float4 w2 = *(const float4*)(Wb + 256 + 8 * lnl + 4 * t);
        bl = fmaf(o[4 * t], w0.x, bl); bl = fmaf(o[4 * t + 1], w0.y, bl);
        bl = fmaf(o[4 * t + 2], w0.z, bl); bl = fmaf(o[4 * t + 3], w0.w, bl);
        bl = fmaf(x[4 * t], w1.x, bl); bl = fmaf(x[4 * t + 1], w1.y, bl);
        bl = fmaf(x[4 * t + 2], w1.z, bl); bl = fmaf(x[4 * t + 3], w1.w, bl);
        bl = fmaf(o[4 * t] - x[4 * t], w2.x, bl); bl = fmaf(o[4 * t + 1] - x[4 * t + 1], w2.y, bl);
        bl = fmaf(o[4 * t + 2] - x[4 * t + 2], w2.z, bl); bl = fmaf(o[4 * t + 3] - x[4 * t + 3], w2.w, bl);
    }
    bl = red16(bl);
    float beta = 1.f / (1.f + __expf(-bl));
    float tpre[8];
    {
        uint4 rw = *(const uint4*)(res32 + (size_t)node * 64 + 4 * lnl);
        unsigned rd[4] = {rw.x, rw.y, rw.z, rw.w};
#pragma unroll
        for (int i = 0; i < 8; ++i) {
            float gg = beta * x[i] + (1.f - beta) * o[i];
            gg = 0.5f * gg * (1.f + erff(gg * 0.70710678118654752f));
            float rv = (i & 1) ? bf2f((unsigned short)(rd[i >> 1] >> 16)) : bf2f((unsigned short)rd[i >> 1]);
            tpre[i] = gg + rv;
        }
    }
    float su = 0.f, sq = 0.f;
#pragma unroll
    for (int i = 0; i < 8; ++i) {
        su += tpre[i];
        sq = fmaf(tpre[i], tpre[i], sq);
    }
    su = red16(su);
    sq = red16(sq);
    float mu = su * (1.f / 128.f);
    float var = sq * (1.f / 128.f) - mu * mu;
    float inv = rsqrtf(var + 1e-5f);
    float4 g0 = *(const float4*)(lng + 8 * lnl);
    float4 g1 = *(const float4*)(lng + 8 * lnl + 4);
    float4 b0 = *(const float4*)(lnb + 8 * lnl);
    float4 b1 = *(const float4*)(lnb + 8 * lnl + 4);
    float gg[8] = {g0.x, g0.y, g0.z, g0.w, g1.x, g1.y, g1.z, g1.w};
    float bb[8] = {b0.x, b0.y, b0.z, b0.w, b1.x, b1.y, b1.z, b1.w};
    float ov[8];
#pragma unroll
    for (int i = 0; i < 8; ++i) ov[i] = (tpre[i] - mu) * inv * gg[i] + bb[i];
    if (houtf) {
        float* op = houtf + (size_t)node * 128 + 8 * lnl;
        *(float4*)op = make_float4(ov[0], ov[1], ov[2], ov[3]);
        *(float4*)(op + 4) = make_float4(ov[4], ov[5], ov[6], ov[7]);
    } else {
        unsigned pk[4];
#pragma unroll
        for (int d = 0; d < 4; ++d) pk[d] = packbf(ov[2 * d], ov[2 * d + 1]);
        *(uint4*)(houtb + (size_t)node * 64 + 4 * lnl) = make_uint4(pk[0], pk[1], pk[2], pk[3]);
    }
}

extern "C" void kernel_launch(void* const* d_in, const int* in_sizes, int n_in, void* d_out, int out_size,
                              void* d_ws, size_t ws_size, hipStream_t stream) {
    const float* x = (const float*)d_in[0];
    const int* ei = (const int*)d_in[1];
    const float* ea = (const float*)d_in[2];
    const float* Wi = (const float*)d_in[3];
    const float* bi = (const float*)d_in[4];
    const float* Wq = (const float*)d_in[5];
    const float* bq = (const float*)d_in[6];
    const float* Wk = (const float*)d_in[7];
    const float* bk = (const float*)d_in[8];
    const float* Wv = (const float*)d_in[9];
    const float* bv = (const float*)d_in[10];
    const float* We = (const float*)d_in[11];
    const float* Wskip = (const float*)d_in[12];
    const float* bskip = (const float*)d_in[13];
    const float* Wbeta = (const float*)d_in[14];
    const float* lng = (const float*)d_in[15];
    const float* lnb = (const float*)d_in[16];

    const int* srcp = ei;
    const int* dstp = ei + NEDGES;

    char* p = (char*)d_ws;
    auto alloc = [&](size_t bytes) {
        void* r = (void*)p;
        p += (bytes + 255) & ~(size_t)255;
        return r;
    };
    unsigned* h32 = (unsigned*)alloc((size_t)NNODES * 64 * 4);
    unsigned* q32 = (unsigned*)alloc((size_t)NNODES * 64 * 4);
    unsigned* xr32 = (unsigned*)alloc((size_t)NNODES * 64 * 4);
    unsigned* kv = (unsigned*)alloc((size_t)NNODES * 64 * 4);
    unsigned short* Wit = (unsigned short*)alloc((size_t)DHID * DIN * 2);
    unsigned short* Wt3 = (unsigned short*)alloc((size_t)3 * 512 * DHID * 2);
    int* counts = (int*)alloc((size_t)(NNODES + 768) * 4);  // counts + bfill(256) + dh(256) + dfill(256), one memset
    int* bfill = counts + NNODES;
    int* dh = bfill + 256;
    int* dfill = dh + 256;
    int* dbase = (int*)alloc(256 * 4);
    int* perm = (int*)alloc((size_t)NNODES * 4);
    int* row_ptr = (int*)alloc((size_t)(NNODES + 1) * 4);
    unsigned* esrc = (unsigned*)alloc((size_t)NEDGES * 4);
    unsigned* brec = (unsigned*)alloc((size_t)NEDGES * 4);
    unsigned char* bdst = (unsigned char*)alloc((size_t)NEDGES);
    int* partials = (int*)alloc(256 * 4);

    const int EB = (NEDGES + 255) / 256;  // 3125
    const int NB = (NNODES + 255) / 256;  // 196
    const int WB = NNODES / 16;           // 3125
    const int PB = (DHID * DIN + 3 * 512 * DHID + 255) / 256;  // 896
    const int AB = (NEDGES + CHUNK - 1) / CHUNK;  // 196

    hipMemsetAsync(counts, 0, (size_t)(NNODES + 768) * 4, stream);
    prep_hist<<<PB + EB, 256, 0, stream>>>(Wi, Wq, Wk, Wv, Wskip, Wit, Wt3, dstp, counts, PB);
    gemm_in<<<GBLK, 256, 0, stream>>>(x, Wit, bi, h32, NNODES);
    k_scan_block<<<NB, 256, 0, stream>>>(counts, row_ptr + 1, partials, NNODES, dh);
    k_apply2<<<NB, 256, 0, stream>>>(partials, row_ptr, NNODES, NB, dh, dbase);
    perm_scatter<<<NB, 256, 0, stream>>>(counts, dbase, dfill, perm);
    bin_edges<<<AB, 256, 0, stream>>>(srcp, dstp, ea, row_ptr, bfill, brec, bdst);
    sort_bucket<<<NBUCK, 256, 0, stream>>>(brec, bdst, row_ptr, esrc);

    for (int l = 0; l < 3; ++l) {
        const size_t bo = (size_t)l * 128;
        gemm_qkvs<<<QBLK, 256, 0, stream>>>((const unsigned short*)h32, Wt3 + (size_t)l * 512 * DHID, bq + bo, bk + bo,
                                            bv + bo, bskip + bo, q32, kv, xr32, NNODES);
        node_attn_fuse<<<WB, 256, 0, stream>>>(q32, kv, esrc, We + bo, row_ptr, perm, xr32, h32,
                                               Wbeta + (size_t)l * 384, lng + bo, lnb + bo, h32,
                                               (l == 2) ? (float*)d_out : nullptr);
    }
}

// Round 15
// 311.061 us; speedup vs baseline: 1.0424x; 1.0423x over previous
//
#include <hip/hip_runtime.h>
#include <math.h>

#define NNODES 50000
#define NEDGES 800000
#define DIN 256
#define DHID 128
#define GBLK 391   // 128-row gemm blocks = ceil(50000/128)
#define NBUCK 196  // ceil(50000/256) dst buckets
#define CHUNK 4096 // edges per bin_edges block

typedef __attribute__((ext_vector_type(8))) short short8;
typedef __attribute__((ext_vector_type(4))) float f32x4;
typedef __attribute__((ext_vector_type(2))) float f32x2;

__device__ __forceinline__ unsigned short f2bf(float f) {
    unsigned u = __builtin_bit_cast(unsigned, f);
    u += 0x7fffu + ((u >> 16) & 1u);  // RNE
    return (unsigned short)(u >> 16);
}
__device__ __forceinline__ float bf2f(unsigned short s) {
    return __builtin_bit_cast(float, (unsigned)s << 16);
}
__device__ __forceinline__ unsigned packbf(float a, float b) {
    return (unsigned)f2bf(a) | ((unsigned)f2bf(b) << 16);
}
// DPP helpers: full-rate VALU cross-lane (no LDS)
__device__ __forceinline__ float dpp_xor1(float x) {  // quad_perm [1,0,3,2]
    return __builtin_bit_cast(float, __builtin_amdgcn_update_dpp(0, __builtin_bit_cast(int, x), 0xB1, 0xF, 0xF, true));
}
__device__ __forceinline__ float dpp_xor2(float x) {  // quad_perm [2,3,0,1]
    return __builtin_bit_cast(float, __builtin_amdgcn_update_dpp(0, __builtin_bit_cast(int, x), 0x4E, 0xF, 0xF, true));
}
__device__ __forceinline__ float dpp_hmirror(float x) {  // row_half_mirror
    return __builtin_bit_cast(float, __builtin_amdgcn_update_dpp(0, __builtin_bit_cast(int, x), 0x141, 0xF, 0xF, true));
}
__device__ __forceinline__ float dpp_mirror(float x) {  // row_mirror
    return __builtin_bit_cast(float, __builtin_amdgcn_update_dpp(0, __builtin_bit_cast(int, x), 0x140, 0xF, 0xF, true));
}
__device__ __forceinline__ float red16(float x) {
    x += dpp_xor1(x);
    x += dpp_xor2(x);
    x += dpp_hmirror(x);
    x += dpp_mirror(x);
    return x;
}

// ---------------- weight prep (blocks < pb) + degree histogram (blocks >= pb) ----------------
__global__ __launch_bounds__(256) void prep_hist(const float* __restrict__ Wi, const float* __restrict__ Wq,
                                                 const float* __restrict__ Wk, const float* __restrict__ Wv,
                                                 const float* __restrict__ Ws, unsigned short* __restrict__ Wit,
                                                 unsigned short* __restrict__ Wt3, const int* __restrict__ dst,
                                                 int* __restrict__ counts, int pb) {
    if ((int)blockIdx.x < pb) {
        int idx = blockIdx.x * 256 + threadIdx.x;
        if (idx < DHID * DIN) {
            int n = idx >> 8, kk = idx & 255;
            Wit[idx] = f2bf(Wi[kk * DHID + n]);
        }
        int idx2 = idx - DHID * DIN;
        if (idx2 >= 0 && idx2 < 3 * 512 * DHID) {
            int l = idx2 / (512 * DHID);
            int rem = idx2 - l * 512 * DHID;
            int r = rem >> 7;
            int kk = rem & 127;
            int sel = r >> 7, rl = r & 127;
            const float* srcm = sel == 0 ? Wq : sel == 1 ? Wk : sel == 2 ? Wv : Ws;
            Wt3[idx2] = f2bf(srcm[l * DHID * DHID + kk * DHID + rl]);
        }
    } else {
        int e = (blockIdx.x - pb) * 256 + threadIdx.x;
        if (e < NEDGES) atomicAdd(&counts[dst[e]], 1);
    }
}

// scan counts -> row_ptr+1 partials; ALSO accumulate degree histogram (deg clamp 255) into dh
__global__ __launch_bounds__(256) void k_scan_block(const int* __restrict__ in, int* __restrict__ out,
                                                    int* __restrict__ partials, int n, int* __restrict__ dh) {
    __shared__ int sh[256];
    __shared__ int dhist[256];
    int tid = threadIdx.x;
    int i = blockIdx.x * 256 + tid;
    int vv = (i < n) ? in[i] : 0;
    sh[tid] = vv;
    dhist[tid] = 0;
    __syncthreads();
    if (i < n) atomicAdd(&dhist[min(vv, 255)], 1);
    for (int off = 1; off < 256; off <<= 1) {
        int t = (tid >= off) ? sh[tid - off] : 0;
        __syncthreads();
        sh[tid] += t;
        __syncthreads();
    }
    if (i < n) out[i] = sh[tid];
    if (tid == 255) partials[blockIdx.x] = sh[255];
    __syncthreads();
    int hc = dhist[tid];
    if (hc) atomicAdd(&dh[tid], hc);
}

// apply block prefixes to row_ptr; block 0 also builds dbase = descending-degree exclusive prefix of dh
__global__ __launch_bounds__(256) void k_apply2(const int* __restrict__ partials, int* __restrict__ row_ptr, int n,
                                                int nb, const int* __restrict__ dh, int* __restrict__ dbase) {
    __shared__ int sh[256];
    int tid = threadIdx.x;
    int vv = (tid < nb) ? partials[tid] : 0;
    sh[tid] = vv;
    __syncthreads();
    for (int off = 1; off < 256; off <<= 1) {
        int t = (tid >= off) ? sh[tid - off] : 0;
        __syncthreads();
        sh[tid] += t;
        __syncthreads();
    }
    int i = blockIdx.x * 256 + tid;
    if (i < n) {
        int add = blockIdx.x ? sh[blockIdx.x - 1] : 0;
        row_ptr[i + 1] += add;
    }
    if (i == 0) row_ptr[0] = 0;
    if (blockIdx.x == 0) {
        __syncthreads();
        int c = dh[255 - tid];
        sh[tid] = c;
        __syncthreads();
        for (int off = 1; off < 256; off <<= 1) {
            int t = (tid >= off) ? sh[tid - off] : 0;
            __syncthreads();
            sh[tid] += t;
            __syncthreads();
        }
        dbase[255 - tid] = sh[tid] - c;  // exclusive prefix, highest degree first
    }
}

// LPT permutation: perm = node ids sorted by degree descending (LDS-aggregated counting sort)
__global__ __launch_bounds__(256) void perm_scatter(const int* __restrict__ counts, const int* __restrict__ dbase,
                                                    int* __restrict__ dfill, int* __restrict__ perm) {
    __shared__ int h[256], gb[256], c2[256];
    const int tid = threadIdx.x;
    int i = blockIdx.x * 256 + tid;
    int d = (i < NNODES) ? min(counts[i], 255) : -1;
    h[tid] = 0;
    c2[tid] = 0;
    __syncthreads();
    if (d >= 0) atomicAdd(&h[d], 1);
    __syncthreads();
    int c = h[tid];
    gb[tid] = c ? dbase[tid] + atomicAdd(&dfill[tid], c) : 0;
    __syncthreads();
    if (d >= 0) {
        int r = atomicAdd(&c2[d], 1);
        perm[gb[d] + r] = i;
    }
}

// ---------------- pass A: bin edges by dst>>8 into bucket-grouped intermediate (coalesced writes) ----------------
__global__ __launch_bounds__(256) void bin_edges(const int* __restrict__ src, const int* __restrict__ dst,
                                                 const float* __restrict__ ea, const int* __restrict__ row_ptr,
                                                 int* __restrict__ bfill, unsigned* __restrict__ brec,
                                                 unsigned char* __restrict__ bdst) {
    __shared__ int hist[NBUCK];
    __shared__ int lbase[NBUCK];
    __shared__ int gbase[NBUCK];
    __shared__ int cnt[NBUCK];
    __shared__ unsigned rec4[CHUNK];
    __shared__ unsigned char dl8[CHUNK];
    __shared__ unsigned char bk8[CHUNK];
    const int tid = threadIdx.x;
    const int e0 = blockIdx.x * CHUNK;
    const int n = min(NEDGES - e0, CHUNK);
    for (int i = tid; i < NBUCK; i += 256) hist[i] = 0;
    __syncthreads();
    for (int i = tid; i < n; i += 256) atomicAdd(&hist[dst[e0 + i] >> 8], 1);
    __syncthreads();
    if (tid == 0) {
        int run = 0;
        for (int b = 0; b < NBUCK; ++b) {
            lbase[b] = run;
            run += hist[b];
        }
    }
    __syncthreads();
    for (int b = tid; b < NBUCK; b += 256) {
        int h = hist[b];
        int off = h ? atomicAdd(&bfill[b], h) : 0;
        gbase[b] = row_ptr[b << 8] + off;
        cnt[b] = lbase[b];
    }
    __syncthreads();
    for (int i = tid; i < n; i += 256) {
        int d = dst[e0 + i];
        int b = d >> 8;
        int lp = atomicAdd(&cnt[b], 1);
        rec4[lp] = (unsigned)src[e0 + i] | ((unsigned)f2bf(ea[e0 + i]) << 16);
        dl8[lp] = (unsigned char)(d & 255);
        bk8[lp] = (unsigned char)b;
    }
    __syncthreads();
    for (int i = tid; i < n; i += 256) {
        int b = bk8[i];
        int pos = gbase[b] + (i - lbase[b]);
        brec[pos] = rec4[i];
        bdst[pos] = dl8[i];
    }
}

// ---------------- pass B: within-bucket counting sort; all stores confined to one block's window ----------------
__global__ __launch_bounds__(256) void sort_bucket(const unsigned* __restrict__ brec,
                                                   const unsigned char* __restrict__ bdst,
                                                   const int* __restrict__ row_ptr, unsigned* __restrict__ esrc) {
    __shared__ int rp[257];
    __shared__ int cnt[256];
    const int b = blockIdx.x;
    const int d0 = b << 8;
    const int nmax = min(256, NNODES - d0);
    const int tid = threadIdx.x;
    for (int i = tid; i <= nmax; i += 256) rp[i] = row_ptr[d0 + i];
    cnt[tid] = 0;
    __syncthreads();
    const int base = rp[0], end = rp[nmax];
    for (int i = base + tid; i < end; i += 256) {
        unsigned rec = brec[i];
        int d = bdst[i];
        int rank = atomicAdd(&cnt[d], 1);
        esrc[rp[d] + rank] = rec;
    }
}

// ---------------- input projection: h[M,128](bf16) = x[M,256] @ Wi + bi ----------------
__global__ __launch_bounds__(256) void gemm_in(const float* __restrict__ A, const unsigned short* __restrict__ Wt,
                                               const float* __restrict__ bias, unsigned* __restrict__ h32, int M) {
    __shared__ short As[128 * 128];
    const int tid = threadIdx.x;
    const int lane = tid & 63;
    const int wid = tid >> 6;
    const int row0 = blockIdx.x * 128;
    const int wr = (wid & 1) * 64;
    const int wc = (wid >> 1) * 64;
    f32x4 acc[4][4] = {};
    const int srow = tid >> 1;
    const int sk = (tid & 1) * 64;
    const int grow = min(row0 + srow, M - 1);
    for (int kt = 0; kt < 2; ++kt) {
        const float* ap = A + (size_t)grow * DIN + kt * 128 + sk;
#pragma unroll
        for (int i = 0; i < 8; ++i) {
            float4 f0 = *(const float4*)(ap + i * 8);
            float4 f1 = *(const float4*)(ap + i * 8 + 4);
            short8 s;
            s[0] = f2bf(f0.x); s[1] = f2bf(f0.y); s[2] = f2bf(f0.z); s[3] = f2bf(f0.w);
            s[4] = f2bf(f1.x); s[5] = f2bf(f1.y); s[6] = f2bf(f1.z); s[7] = f2bf(f1.w);
            int g = (sk >> 3) + i;
            *(short8*)(&As[srow * 128 + ((g ^ (srow & 7)) << 3)]) = s;
        }
        __syncthreads();
#pragma unroll
        for (int ks = 0; ks < 4; ++ks) {
            short8 a[4], b[4];
#pragma unroll
            for (int m = 0; m < 4; ++m) {
                int r = wr + m * 16 + (lane & 15);
                int g = ks * 4 + (lane >> 4);
                a[m] = *(const short8*)(&As[r * 128 + ((g ^ (r & 7)) << 3)]);
            }
#pragma unroll
            for (int n = 0; n < 4; ++n) {
                int c = wc + n * 16 + (lane & 15);
                b[n] = *(const short8*)(Wt + (size_t)c * DIN + kt * 128 + ks * 32 + (lane >> 4) * 8);
            }
#pragma unroll
            for (int m = 0; m < 4; ++m)
#pragma unroll
                for (int n = 0; n < 4; ++n)
                    acc[m][n] = __builtin_amdgcn_mfma_f32_16x16x32_bf16(a[m], b[n], acc[m][n], 0, 0, 0);
        }
        __syncthreads();
    }
    // epilogue: per-wave LDS repack (reuse As) -> coalesced uint4 stores
    float* my = ((float*)As) + wid * 1024;
    float bb[4];
#pragma unroll
    for (int n = 0; n < 4; ++n) bb[n] = bias[wc + n * 16 + (lane & 15)];
    const int rr = lane >> 2;
    const int cb = lane & 3;
#pragma unroll
    for (int m = 0; m < 4; ++m) {
#pragma unroll
        for (int n = 0; n < 4; ++n) {
            int lc = n * 16 + (lane & 15);
#pragma unroll
            for (int j = 0; j < 4; ++j) {
                int row = (lane >> 4) * 4 + j;
                my[row * 64 + (((lc >> 2) ^ (row & 7)) << 2) + (lc & 3)] = acc[m][n][j] + bb[n];
            }
        }
        float vals[16];
#pragma unroll
        for (int s = 0; s < 4; ++s) {
            int gx = (cb * 4 + s) ^ (rr & 7);
            f32x4 t4 = *(const f32x4*)(my + rr * 64 + gx * 4);
            vals[s * 4 + 0] = t4.x; vals[s * 4 + 1] = t4.y; vals[s * 4 + 2] = t4.z; vals[s * 4 + 3] = t4.w;
        }
        int grow2 = row0 + wr + m * 16 + rr;
        if (grow2 < M) {
            unsigned pk[8];
#pragma unroll
            for (int d = 0; d < 8; ++d) pk[d] = packbf(vals[2 * d], vals[2 * d + 1]);
            unsigned* op = h32 + (size_t)grow2 * 64 + (wc >> 1) + cb * 8;
            *(uint4*)op = make_uint4(pk[0], pk[1], pk[2], pk[3]);
            *(uint4*)(op + 4) = make_uint4(pk[4], pk[5], pk[6], pk[7]);
        }
    }
}

// ---------------- fused q/k/v/skip GEMM from bf16 h (128-row / 512-thread, reverted) ----------------
__global__ __launch_bounds__(512) void gemm_qkvs(const unsigned short* __restrict__ A,
                                                 const unsigned short* __restrict__ Wt, const float* __restrict__ bq,
                                                 const float* __restrict__ bk, const float* __restrict__ bv,
                                                 const float* __restrict__ bs, unsigned* __restrict__ q32,
                                                 unsigned* __restrict__ kv, unsigned* __restrict__ xr32, int M) {
    __shared__ short As[128 * 128];
    const int tid = threadIdx.x;
    const int lane = tid & 63;
    const int wid = tid >> 6;
    const int row0 = blockIdx.x * 128;
    const int sel = wid >> 2;  // 0: q/skip, 1: k/v
    const int wr = (wid & 1) * 64;
    const int wc = ((wid >> 1) & 1) * 64;
    f32x4 acc0[4][4] = {}, acc1[4][4] = {};
    {
        const int srow = tid >> 2;
        const int sk = (tid & 3) * 32;
        const int grow = min(row0 + srow, M - 1);
        const unsigned short* ap = A + (size_t)grow * DHID + sk;
#pragma unroll
        for (int i = 0; i < 4; ++i) {
            short8 s = *(const short8*)(ap + i * 8);
            int g = (sk >> 3) + i;
            *(short8*)(&As[srow * 128 + ((g ^ (srow & 7)) << 3)]) = s;
        }
    }
    __syncthreads();
    const int b0base = sel ? 128 : 0;    // k : q
    const int b1base = sel ? 256 : 384;  // v : skip
#pragma unroll
    for (int ks = 0; ks < 4; ++ks) {
        short8 a[4], b0[4], b1[4];
#pragma unroll
        for (int m = 0; m < 4; ++m) {
            int r = wr + m * 16 + (lane & 15);
            int g = ks * 4 + (lane >> 4);
            a[m] = *(const short8*)(&As[r * 128 + ((g ^ (r & 7)) << 3)]);
        }
#pragma unroll
        for (int n = 0; n < 4; ++n) {
            int rb = wc + n * 16 + (lane & 15);
            b0[n] = *(const short8*)(Wt + (size_t)(b0base + rb) * DHID + ks * 32 + (lane >> 4) * 8);
            b1[n] = *(const short8*)(Wt + (size_t)(b1base + rb) * DHID + ks * 32 + (lane >> 4) * 8);
        }
#pragma unroll
        for (int m = 0; m < 4; ++m)
#pragma unroll
            for (int n = 0; n < 4; ++n) {
                acc0[m][n] = __builtin_amdgcn_mfma_f32_16x16x32_bf16(a[m], b0[n], acc0[m][n], 0, 0, 0);
                acc1[m][n] = __builtin_amdgcn_mfma_f32_16x16x32_bf16(a[m], b1[n], acc1[m][n], 0, 0, 0);
            }
    }
    __syncthreads();  // done reading As; reuse as repack buffer
    float* my = ((float*)As) + wid * 1024;
    const float* bias0 = sel ? bk : bq;
    const float* bias1 = sel ? bv : bs;
    float bb0[4], bb1[4];
#pragma unroll
    for (int n = 0; n < 4; ++n) {
        int c = wc + n * 16 + (lane & 15);
        bb0[n] = bias0[c];
        bb1[n] = bias1[c];
    }
    const int rr = lane >> 2;
    const int cb = lane & 3;
#pragma unroll
    for (int m = 0; m < 4; ++m) {
        float vals0[16], vals1[16];
#pragma unroll
        for (int n = 0; n < 4; ++n) {
            int lc = n * 16 + (lane & 15);
#pragma unroll
            for (int j = 0; j < 4; ++j) {
                int row = (lane >> 4) * 4 + j;
                my[row * 64 + (((lc >> 2) ^ (row & 7)) << 2) + (lc & 3)] = acc0[m][n][j] + bb0[n];
            }
        }
#pragma unroll
        for (int s = 0; s < 4; ++s) {
            int gx = (cb * 4 + s) ^ (rr & 7);
            f32x4 t4 = *(const f32x4*)(my + rr * 64 + gx * 4);
            vals0[s * 4 + 0] = t4.x; vals0[s * 4 + 1] = t4.y; vals0[s * 4 + 2] = t4.z; vals0[s * 4 + 3] = t4.w;
        }
#pragma unroll
        for (int n = 0; n < 4; ++n) {
            int lc = n * 16 + (lane & 15);
#pragma unroll
            for (int j = 0; j < 4; ++j) {
                int row = (lane >> 4) * 4 + j;
                my[row * 64 + (((lc >> 2) ^ (row & 7)) << 2) + (lc & 3)] = acc1[m][n][j] + bb1[n];
            }
        }
#pragma unroll
        for (int s = 0; s < 4; ++s) {
            int gx = (cb * 4 + s) ^ (rr & 7);
            f32x4 t4 = *(const f32x4*)(my + rr * 64 + gx * 4);
            vals1[s * 4 + 0] = t4.x; vals1[s * 4 + 1] = t4.y; vals1[s * 4 + 2] = t4.z; vals1[s * 4 + 3] = t4.w;
        }
        int grow2 = row0 + wr + m * 16 + rr;
        if (grow2 < M) {
            size_t obase = (size_t)grow2 * 64 + (wc >> 1) + cb * 8;
            if (sel == 0) {
                unsigned p0[8], p1[8];
#pragma unroll
                for (int d = 0; d < 8; ++d) {
                    p0[d] = packbf(vals0[2 * d], vals0[2 * d + 1]);
                    p1[d] = packbf(vals1[2 * d], vals1[2 * d + 1]);
                }
                *(uint4*)(q32 + obase) = make_uint4(p0[0], p0[1], p0[2], p0[3]);
                *(uint4*)(q32 + obase + 4) = make_uint4(p0[4], p0[5], p0[6], p0[7]);
                *(uint4*)(xr32 + obase) = make_uint4(p1[0], p1[1], p1[2], p1[3]);
                *(uint4*)(xr32 + obase + 4) = make_uint4(p1[4], p1[5], p1[6], p1[7]);
            } else {
                unsigned pk[8];
#pragma unroll
                for (int d = 0; d < 8; ++d) {
                    unsigned u = (unsigned)__builtin_amdgcn_cvt_pk_fp8_f32(vals0[2 * d], vals0[2 * d + 1], 0, false);
                    u = (unsigned)__builtin_amdgcn_cvt_pk_fp8_f32(vals1[2 * d], vals1[2 * d + 1], (int)u, true);
                    pk[d] = u;
                }
                *(uint4*)(kv + obase) = make_uint4(pk[0], pk[1], pk[2], pk[3]);
                *(uint4*)(kv + obase + 4) = make_uint4(pk[4], pk[5], pk[6], pk[7]);
            }
        }
    }
}

// ---------------- per-node attention + beta-gate + GELU + LayerNorm ----------------
// 4 nodes per wave via LPT perm: 16-lane group per node, lane owns 8 channels (1 uint4 kv).
// Quad processing: 4 edges/iteration, 2-quad register pipeline (8 kv rows in flight, prefetch distance 8 slots).
// v decoded inline from kwA at accumulation (no vj spill). Zero LDS.
// Algebra: logit = q·k + av*(q·we);  out = (Σw·v + (Σw·av)·we)/Σw. exp2-domain, defer-max.
// houtb may alias res32 (same-wave RAW only).
__global__ __launch_bounds__(256) void node_attn_fuse(const unsigned* __restrict__ q32,
                                                      const unsigned* __restrict__ kv, const unsigned* __restrict__ esrc,
                                                      const float* __restrict__ We, const int* __restrict__ row_ptr,
                                                      const int* __restrict__ perm, const unsigned* __restrict__ xr32,
                                                      const unsigned* res32, const float* __restrict__ Wb,
                                                      const float* __restrict__ lng, const float* __restrict__ lnb,
                                                      unsigned* houtb, float* houtf) {
    const int tid = threadIdx.x;
    const int lane = tid & 63;
    const int lnl = lane & 15;    // lane within node group
    const int gbase = lane & 48;  // group base lane
    const int node = perm[blockIdx.x * 16 + (tid >> 4)];  // LPT order; 50000 = 3125*16 exact
    const int base = row_ptr[node], end = row_ptr[node + 1];
    const float SC = 0.25505654047688565f;  // (1/sqrt(32)) * log2(e)
    const float THR = 8.0f;

    float qv[8], wev[8];
    {
        uint4 qw = *(const uint4*)(q32 + (size_t)node * 64 + 4 * lnl);
        unsigned qd[4] = {qw.x, qw.y, qw.z, qw.w};
#pragma unroll
        for (int t = 0; t < 4; ++t) {
            qv[2 * t] = bf2f((unsigned short)qd[t]) * SC;
            qv[2 * t + 1] = bf2f((unsigned short)(qd[t] >> 16)) * SC;
        }
        float4 wlo = *(const float4*)(We + 8 * lnl);
        float4 whi = *(const float4*)(We + 8 * lnl + 4);
        wev[0] = wlo.x; wev[1] = wlo.y; wev[2] = wlo.z; wev[3] = wlo.w;
        wev[4] = whi.x; wev[5] = whi.y; wev[6] = whi.z; wev[7] = whi.w;
    }
    float qwe;
    {
        float s = 0.f;
#pragma unroll
        for (int i = 0; i < 8; ++i) s = fmaf(qv[i], wev[i], s);
        s += dpp_xor1(s);
        s += dpp_xor2(s);
        qwe = s;
    }

    float m = -1e30f, sden = 0.f, tacc = 0.f;
    float acc[8] = {};
    const unsigned* kvp = kv + 4 * lnl;

    for (int off = 0; ; off += 16) {
        int cnt = min(end - base - off, 16);  // per-group; may be <= 0
        if (__all(cnt <= 0)) break;
        unsigned u_l = 0;
        if (lnl < cnt) u_l = esrc[base + off + lnl];
        int cm = max(cnt, 0);
        cm = max(cm, __shfl_xor(cm, 16));
        cm = max(cm, __shfl_xor(cm, 32));
        // 2-quad pipeline: A = slots j..j+3 (being consumed), B = slots j+4..j+7 (in flight)
        unsigned ueA[4], ueB[4];
        uint4 kwA[4], kwB[4];
#pragma unroll
        for (int s = 0; s < 4; ++s) {
            ueA[s] = (unsigned)__shfl((int)u_l, gbase + s);
            kwA[s] = *(const uint4*)(kvp + (size_t)(ueA[s] & 0xFFFFu) * 64);
        }
#pragma unroll
        for (int s = 0; s < 4; ++s) {
            ueB[s] = (unsigned)__shfl((int)u_l, gbase + 4 + s);
            kwB[s] = *(const uint4*)(kvp + (size_t)(ueB[s] & 0xFFFFu) * 64);
        }
        for (int j = 0; j < cm; j += 4) {
            float p[4], av[4];
#pragma unroll
            for (int s = 0; s < 4; ++s) {
                av[s] = bf2f((unsigned short)(ueA[s] >> 16));
                unsigned kd[4] = {kwA[s].x, kwA[s].y, kwA[s].z, kwA[s].w};
                float pp = 0.f;
#pragma unroll
                for (int t = 0; t < 4; ++t) {
                    f32x2 kk = __builtin_amdgcn_cvt_pk_f32_fp8((int)kd[t], false);
                    pp = fmaf(qv[2 * t], kk.x, pp);
                    pp = fmaf(qv[2 * t + 1], kk.y, pp);
                }
                p[s] = pp;
            }
#pragma unroll
            for (int s = 0; s < 4; ++s) {
                p[s] += dpp_xor1(p[s]);
                p[s] += dpp_xor2(p[s]);  // head dot (4 lanes = 32 ch)
                p[s] = fmaf(av[s], qwe, p[s]);
                p[s] = (j + s < cnt) ? p[s] : -3e38f;
            }
            float pm = fmaxf(fmaxf(p[0], p[1]), fmaxf(p[2], p[3]));
            float w[4];
            if (__any(pm - m > THR)) {  // rare: max update + rescale (taken on first quad)
                float mn2 = fmaxf(m, pm);
                float sc = exp2f(m - mn2);
#pragma unroll
                for (int s = 0; s < 4; ++s) w[s] = exp2f(p[s] - mn2);
                sden = fmaf(sden, sc, (w[0] + w[1]) + (w[2] + w[3]));
                tacc = fmaf(tacc, sc, fmaf(w[0], av[0], w[1] * av[1]) + fmaf(w[2], av[2], w[3] * av[3]));
#pragma unroll
                for (int t = 0; t < 4; ++t) {
                    f32x2 v0 = __builtin_amdgcn_cvt_pk_f32_fp8((int)kwA[0].x, true);  // placeholder replaced below
                    (void)v0;
                }
#pragma unroll
                for (int i = 0; i < 8; ++i) acc[i] *= sc;
#pragma unroll
                for (int s = 0; s < 4; ++s) {
                    unsigned kd[4] = {kwA[s].x, kwA[s].y, kwA[s].z, kwA[s].w};
#pragma unroll
                    for (int t = 0; t < 4; ++t) {
                        f32x2 vv = __builtin_amdgcn_cvt_pk_f32_fp8((int)kd[t], true);
                        acc[2 * t] = fmaf(w[s], vv.x, acc[2 * t]);
                        acc[2 * t + 1] = fmaf(w[s], vv.y, acc[2 * t + 1]);
                    }
                }
                m = mn2;
            } else {  // common path: 4 independent exp2s
#pragma unroll
                for (int s = 0; s < 4; ++s) w[s] = exp2f(p[s] - m);
                sden += (w[0] + w[1]) + (w[2] + w[3]);
                tacc += fmaf(w[0], av[0], w[1] * av[1]) + fmaf(w[2], av[2], w[3] * av[3]);
#pragma unroll
                for (int s = 0; s < 4; ++s) {
                    unsigned kd[4] = {kwA[s].x, kwA[s].y, kwA[s].z, kwA[s].w};
#pragma unroll
                    for (int t = 0; t < 4; ++t) {
                        f32x2 vv = __builtin_amdgcn_cvt_pk_f32_fp8((int)kd[t], true);
                        acc[2 * t] = fmaf(w[s], vv.x, acc[2 * t]);
                        acc[2 * t + 1] = fmaf(w[s], vv.y, acc[2 * t + 1]);
                    }
                }
            }
            // shift pipeline; prefetch next quad at distance 8 (padding slots -> row 0, L2-hot)
#pragma unroll
            for (int s = 0; s < 4; ++s) {
                ueA[s] = ueB[s];
                kwA[s] = kwB[s];
            }
            if (j + 8 < cm) {
#pragma unroll
                for (int s = 0; s < 4; ++s) {
                    int slot = j + 8 + s;
                    slot = slot < 16 ? slot : 0;
                    ueB[s] = (unsigned)__shfl((int)u_l, gbase + slot);
                    kwB[s] = *(const uint4*)(kvp + (size_t)(ueB[s] & 0xFFFFu) * 64);
                }
            }
        }
    }

    float rden = 1.f / (sden + 1e-16f);
    float o[8];
#pragma unroll
    for (int i = 0; i < 8; ++i) o[i] = fmaf(tacc, wev[i], acc[i]) * rden;

    // ---- fused epilogue in the same 8-ch/lane layout (reduces within 16-lane group) ----
    float x[8];
    {
        uint4 xw = *(const uint4*)(xr32 + (size_t)node * 64 + 4 * lnl);
        unsigned xd[4] = {xw.x, xw.y, xw.z, xw.w};
#pragma unroll
        for (int t = 0; t < 4; ++t) {
            x[2 * t] = bf2f((unsigned short)xd[t]);
            x[2 * t + 1] = bf2f((unsigned short)(xd[t] >> 16));
        }
    }
    float bl = 0.f;
#pragma unroll
    for (int t = 0; t < 2; ++t) {
        float4 w0 = *(const float4*)(Wb + 8 * lnl + 4 * t);
        float4 w1 = *(const float4*)(Wb + 128 + 8 * lnl + 4 * t);
        float4 w2 = *(const float4*)(Wb + 256 + 8 * lnl + 4 * t);
        bl = fmaf(o[4 * t], w0.x, bl); bl = fmaf(o[4 * t + 1], w0.y, bl);
        bl = fmaf(o[4 * t + 2], w0.z, bl); bl = fmaf(o[4 * t + 3], w0.w, bl);
        bl = fmaf(x[4 * t], w1.x, bl); bl = fmaf(x[4 * t + 1], w1.y, bl);
        bl = fmaf(x[4 * t + 2], w1.z, bl); bl = fmaf(x[4 * t + 3], w1.w, bl);
        bl = fmaf(o[4 * t] - x[4 * t], w2.x, bl); bl = fmaf(o[4 * t + 1] - x[4 * t + 1], w2.y, bl);
        bl = fmaf(o[4 * t + 2] - x[4 * t + 2], w2.z, bl); bl = fmaf(o[4 * t + 3] - x[4 * t + 3], w2.w, bl);
    }
    bl = red16(bl);
    float beta = 1.f / (1.f + __expf(-bl));
    float tpre[8];
    {
        uint4 rw = *(const uint4*)(res32 + (size_t)node * 64 + 4 * lnl);
        unsigned rd[4] = {rw.x, rw.y, rw.z, rw.w};
#pragma unroll
        for (int i = 0; i < 8; ++i) {
            float gg = beta * x[i] + (1.f - beta) * o[i];
            gg = 0.5f * gg * (1.f + erff(gg * 0.70710678118654752f));
            float rv = (i & 1) ? bf2f((unsigned short)(rd[i >> 1] >> 16)) : bf2f((unsigned short)rd[i >> 1]);
            tpre[i] = gg + rv;
        }
    }
    float su = 0.f, sq = 0.f;
#pragma unroll
    for (int i = 0; i < 8; ++i) {
        su += tpre[i];
        sq = fmaf(tpre[i], tpre[i], sq);
    }
    su = red16(su);
    sq = red16(sq);
    float mu = su * (1.f / 128.f);
    float var = sq * (1.f / 128.f) - mu * mu;
    float inv = rsqrtf(var + 1e-5f);
    float4 g0 = *(const float4*)(lng + 8 * lnl);
    float4 g1 = *(const float4*)(lng + 8 * lnl + 4);
    float4 b0 = *(const float4*)(lnb + 8 * lnl);
    float4 b1 = *(const float4*)(lnb + 8 * lnl + 4);
    float gg[8] = {g0.x, g0.y, g0.z, g0.w, g1.x, g1.y, g1.z, g1.w};
    float bb[8] = {b0.x, b0.y, b0.z, b0.w, b1.x, b1.y, b1.z, b1.w};
    float ov[8];
#pragma unroll
    for (int i = 0; i < 8; ++i) ov[i] = (tpre[i] - mu) * inv * gg[i] + bb[i];
    if (houtf) {
        float* op = houtf + (size_t)node * 128 + 8 * lnl;
        *(float4*)op = make_float4(ov[0], ov[1], ov[2], ov[3]);
        *(float4*)(op + 4) = make_float4(ov[4], ov[5], ov[6], ov[7]);
    } else {
        unsigned pk[4];
#pragma unroll
        for (int d = 0; d < 4; ++d) pk[d] = packbf(ov[2 * d], ov[2 * d + 1]);
        *(uint4*)(houtb + (size_t)node * 64 + 4 * lnl) = make_uint4(pk[0], pk[1], pk[2], pk[3]);
    }
}

extern "C" void kernel_launch(void* const* d_in, const int* in_sizes, int n_in, void* d_out, int out_size,
                              void* d_ws, size_t ws_size, hipStream_t stream) {
    const float* x = (const float*)d_in[0];
    const int* ei = (const int*)d_in[1];
    const float* ea = (const float*)d_in[2];
    const float* Wi = (const float*)d_in[3];
    const float* bi = (const float*)d_in[4];
    const float* Wq = (const float*)d_in[5];
    const float* bq = (const float*)d_in[6];
    const float* Wk = (const float*)d_in[7];
    const float* bk = (const float*)d_in[8];
    const float* Wv = (const float*)d_in[9];
    const float* bv = (const float*)d_in[10];
    const float* We = (const float*)d_in[11];
    const float* Wskip = (const float*)d_in[12];
    const float* bskip = (const float*)d_in[13];
    const float* Wbeta = (const float*)d_in[14];
    const float* lng = (const float*)d_in[15];
    const float* lnb = (const float*)d_in[16];

    const int* srcp = ei;
    const int* dstp = ei + NEDGES;

    char* p = (char*)d_ws;
    auto alloc = [&](size_t bytes) {
        void* r = (void*)p;
        p += (bytes + 255) & ~(size_t)255;
        return r;
    };
    unsigned* h32 = (unsigned*)alloc((size_t)NNODES * 64 * 4);
    unsigned* q32 = (unsigned*)alloc((size_t)NNODES * 64 * 4);
    unsigned* xr32 = (unsigned*)alloc((size_t)NNODES * 64 * 4);
    unsigned* kv = (unsigned*)alloc((size_t)NNODES * 64 * 4);
    unsigned short* Wit = (unsigned short*)alloc((size_t)DHID * DIN * 2);
    unsigned short* Wt3 = (unsigned short*)alloc((size_t)3 * 512 * DHID * 2);
    int* counts = (int*)alloc((size_t)(NNODES + 768) * 4);  // counts + bfill(256) + dh(256) + dfill(256)
    int* bfill = counts + NNODES;
    int* dh = bfill + 256;
    int* dfill = dh + 256;
    int* dbase = (int*)alloc(256 * 4);
    int* perm = (int*)alloc((size_t)NNODES * 4);
    int* row_ptr = (int*)alloc((size_t)(NNODES + 1) * 4);
    unsigned* esrc = (unsigned*)alloc((size_t)NEDGES * 4);
    unsigned* brec = (unsigned*)alloc((size_t)NEDGES * 4);
    unsigned char* bdst = (unsigned char*)alloc((size_t)NEDGES);
    int* partials = (int*)alloc(256 * 4);

    const int EB = (NEDGES + 255) / 256;  // 3125
    const int NB = (NNODES + 255) / 256;  // 196
    const int WB = NNODES / 16;           // 3125
    const int PB = (DHID * DIN + 3 * 512 * DHID + 255) / 256;  // 896
    const int AB = (NEDGES + CHUNK - 1) / CHUNK;  // 196

    hipMemsetAsync(counts, 0, (size_t)(NNODES + 768) * 4, stream);
    prep_hist<<<PB + EB, 256, 0, stream>>>(Wi, Wq, Wk, Wv, Wskip, Wit, Wt3, dstp, counts, PB);
    gemm_in<<<GBLK, 256, 0, stream>>>(x, Wit, bi, h32, NNODES);
    k_scan_block<<<NB, 256, 0, stream>>>(counts, row_ptr + 1, partials, NNODES, dh);
    k_apply2<<<NB, 256, 0, stream>>>(partials, row_ptr, NNODES, NB, dh, dbase);
    perm_scatter<<<NB, 256, 0, stream>>>(counts, dbase, dfill, perm);
    bin_edges<<<AB, 256, 0, stream>>>(srcp, dstp, ea, row_ptr, bfill, brec, bdst);
    sort_bucket<<<NBUCK, 256, 0, stream>>>(brec, bdst, row_ptr, esrc);

    for (int l = 0; l < 3; ++l) {
        const size_t bo = (size_t)l * 128;
        gemm_qkvs<<<GBLK, 512, 0, stream>>>((const unsigned short*)h32, Wt3 + (size_t)l * 512 * DHID, bq + bo, bk + bo,
                                            bv + bo, bskip + bo, q32, kv, xr32, NNODES);
        node_attn_fuse<<<WB, 256, 0, stream>>>(q32, kv, esrc, We + bo, row_ptr, perm, xr32, h32,
                                               Wbeta + (size_t)l * 384, lng + bo, lnb + bo, h32,
                                               (l == 2) ? (float*)d_out : nullptr);
    }
}